// Round 7
// baseline (403.559 us; speedup 1.0000x reference)
//
#include <hip/hip_runtime.h>
#include <hip/hip_cooperative_groups.h>
namespace cg = cooperative_groups;

#define BATCH   4096
#define IN_SZ   512
#define NQ      12
#define OUT_SZ  256
#define DEPTH   3
#define NST     4096   // 2^NQ
#define BN_EPS  1e-5f

// ---- ws layout (in floats) — R20 base ----
#define OFF_ENC    0            // 4096*12 = 49152
#define OFF_BN1M   49152
#define OFF_BN1R   49168
#define OFF_GU     49184        // 288
#define OFF_GF     49568        // DEPTH*9*8 = 216 (pad 224)
#define OFF_PROBS  49792        // 49152
#define OFF_PMEAN  98944
#define OFF_COV    98960        // 144
#define OFF_GG     99104        // DEPTH*2*8 = 48

typedef float v2f __attribute__((ext_vector_type(2)));
typedef float v4f __attribute__((ext_vector_type(4)));
#define SW2(a) __builtin_shufflevector(a, a, 1, 0)

// =====================================================================================
// R23: cooperative mega-kernel. LESSONS driving it (measured):
//   R17/R21/R22 — per-slot tricks fail: atomic tails +11us; serialized agent-scope
//   atomic-load reduce +84us; hipMemsetAsync is a slot too (+8 vs R20).
//   ~60us of the R20 total is dispatch-slot overhead across 4-5 slots -> remove the
//   slots themselves with ONE hipLaunchCooperativeKernel + 4 grid.sync().
//   Grid sized via occupancy query (32KB LDS/block limits residency); hard fallback
//   to the proven 5-kernel path if cooperative launch is rejected.
// k_quantum core math unchanged from R20 (113.9us): 3-pass C->B->A schedule,
//   CRY->U fusion (gF), CRY3/7 defusion-by-selection (gG), per-block qvec dedup.
// Other lessons: R10 no waves_per_eu; R12 no padded atomics; R16 no v2f coeff tables;
//   R19 v_pk_*_f32 is HALF-RATE on gfx950.
// =====================================================================================

// ---------------- phase bodies (shared by mega kernel and fallback kernels) ----------

// gate prep: one 256-thread work item
__device__ __forceinline__ void gate_prep(int t, const float* __restrict__ rot,
                                          const float* __restrict__ ent,
                                          float* __restrict__ gU, float* __restrict__ gF,
                                          float* __restrict__ gG) {
    if (t < DEPTH * NQ) {
        float ax = rot[t * 3 + 0] * 0.5f;
        float ay = rot[t * 3 + 1] * 0.5f;
        float az = rot[t * 3 + 2] * 0.5f;
        float cx = cosf(ax), sx = sinf(ax);
        float cy = cosf(ay), sy = sinf(ay);
        float cz = cosf(az), sz = sinf(az);
        float m00r =  cy * cx, m00i =  sy * sx;
        float m01r = -sy * cx, m01i = -cy * sx;
        float m10r =  sy * cx, m10i = -cy * sx;
        float m11r =  cy * cx, m11i = -sy * sx;
        float* o = gU + t * 8;
        o[0] = cz * m00r + sz * m00i;  o[1] = cz * m00i - sz * m00r;
        o[2] = cz * m01r + sz * m01i;  o[3] = cz * m01i - sz * m01r;
        o[4] = cz * m10r - sz * m10i;  o[5] = cz * m10i + sz * m10r;
        o[6] = cz * m11r - sz * m11i;  o[7] = cz * m11i + sz * m11r;
    }
    // fused products P = Ry(theta_c) * U_{c+1} for chain CRYs c in {0,1,2, 4,5,6, 8,9,10}
    if (t >= 128 && t - 128 < DEPTH * 9) {
        int i = t - 128;              // 0..26
        int l = i / 9, k = i % 9;
        int c = k + k / 3;            // 0,1,2,4,5,6,8,9,10
        int tq = c + 1;
        const float* rr = rot + (l * NQ + tq) * 3;
        float ax = rr[0] * 0.5f, ay = rr[1] * 0.5f, az = rr[2] * 0.5f;
        float cx = cosf(ax), sx = sinf(ax);
        float cy = cosf(ay), sy = sinf(ay);
        float cz = cosf(az), sz = sinf(az);
        float m00r =  cy * cx, m00i =  sy * sx;
        float m01r = -sy * cx, m01i = -cy * sx;
        float m10r =  sy * cx, m10i = -cy * sx;
        float m11r =  cy * cx, m11i = -sy * sx;
        float u0 = cz * m00r + sz * m00i, u1 = cz * m00i - sz * m00r;
        float u2 = cz * m01r + sz * m01i, u3 = cz * m01i - sz * m01r;
        float u4 = cz * m10r - sz * m10i, u5 = cz * m10i + sz * m10r;
        float u6 = cz * m11r - sz * m11i, u7 = cz * m11i + sz * m11r;
        float th = ent[l * (NQ - 1) + c] * 0.5f;
        float c_ = cosf(th), s_ = sinf(th);
        float* o = gF + i * 8;
        o[0] = c_ * u0 - s_ * u4;  o[1] = c_ * u1 - s_ * u5;
        o[2] = c_ * u2 - s_ * u6;  o[3] = c_ * u3 - s_ * u7;
        o[4] = s_ * u0 + c_ * u4;  o[5] = s_ * u1 + c_ * u5;
        o[6] = s_ * u2 + c_ * u6;  o[7] = s_ * u3 + c_ * u7;
    }
    // fused products for the thread-bit CRYs c in {3,7} (R20)
    if (t >= 160 && t - 160 < DEPTH * 2) {
        int i = t - 160;              // 0..5
        int l = i >> 1;
        int c = (i & 1) ? 7 : 3;
        int tq = c + 1;
        const float* rr = rot + (l * NQ + tq) * 3;
        float ax = rr[0] * 0.5f, ay = rr[1] * 0.5f, az = rr[2] * 0.5f;
        float cx = cosf(ax), sx = sinf(ax);
        float cy = cosf(ay), sy = sinf(ay);
        float cz = cosf(az), sz = sinf(az);
        float m00r =  cy * cx, m00i =  sy * sx;
        float m01r = -sy * cx, m01i = -cy * sx;
        float m10r =  sy * cx, m10i = -cy * sx;
        float m11r =  cy * cx, m11i = -sy * sx;
        float u0 = cz * m00r + sz * m00i, u1 = cz * m00i - sz * m00r;
        float u2 = cz * m01r + sz * m01i, u3 = cz * m01i - sz * m01r;
        float u4 = cz * m10r - sz * m10i, u5 = cz * m10i + sz * m10r;
        float u6 = cz * m11r - sz * m11i, u7 = cz * m11i + sz * m11r;
        float th = ent[l * (NQ - 1) + c] * 0.5f;
        float c_ = cosf(th), s_ = sinf(th);
        float* o = gG + (l * 2 + (i & 1)) * 8;
        o[0] = c_ * u0 - s_ * u4;  o[1] = c_ * u1 - s_ * u5;
        o[2] = c_ * u2 - s_ * u6;  o[3] = c_ * u3 - s_ * u7;
        o[4] = s_ * u0 + c_ * u4;  o[5] = s_ * u1 + c_ * u5;
        o[6] = s_ * u2 + c_ * u6;  o[7] = s_ * u3 + c_ * u7;
    }
}

// encode: one item = 4 rows (wave-per-row), no LDS, no barriers
__device__ __forceinline__ void encode_rows(int it, int t, const float* __restrict__ x,
                                            const float* __restrict__ w,
                                            const float* __restrict__ bvec,
                                            float* __restrict__ enc) {
    int wv = t >> 6, lane = t & 63;
    int row = it * 4 + wv;
    const float4* xr = (const float4*)(x + row * IN_SZ) + lane * 2;
    float4 xa = xr[0], xb = xr[1];
    float acc[NQ];
    #pragma unroll
    for (int q = 0; q < NQ; q++) {
        const float4* wr = (const float4*)(w + q * IN_SZ) + lane * 2;
        float4 wa = wr[0], wb = wr[1];
        float d = xa.x*wa.x + xa.y*wa.y + xa.z*wa.z + xa.w*wa.w
                + xb.x*wb.x + xb.y*wb.y + xb.z*wb.z + xb.w*wb.w;
        #pragma unroll
        for (int o = 32; o > 0; o >>= 1) d += __shfl_down(d, o, 64);
        acc[q] = d;
    }
    if (lane == 0) {
        float* er = enc + row * NQ;
        #pragma unroll
        for (int q = 0; q < NQ; q++) er[q] = acc[q] + bvec[q];
    }
}

// bn1 stats: one item = one feature j; 256 threads; scr = 16 floats of LDS
__device__ __forceinline__ void bnstats_item(int j, int t, const float* __restrict__ enc,
                                             float* __restrict__ bn1m, float* __restrict__ bn1r,
                                             float* __restrict__ scr) {
    float s = 0.f, s2 = 0.f;
    for (int bb = t; bb < BATCH; bb += 256) {
        float v = enc[bb * NQ + j];
        s += v; s2 += v * v;
    }
    #pragma unroll
    for (int o = 32; o > 0; o >>= 1) { s += __shfl_down(s, o, 64); s2 += __shfl_down(s2, o, 64); }
    int lane = t & 63, w = t >> 6;
    __syncthreads();
    if (lane == 0) { scr[w] = s; scr[8 + w] = s2; }
    __syncthreads();
    if (t == 0) {
        float S  = scr[0] + scr[1] + scr[2] + scr[3];
        float S2 = scr[8] + scr[9] + scr[10] + scr[11];
        float mean = S / (float)BATCH;
        float var  = S2 / (float)BATCH - mean * mean;
        bn1m[j] = mean;
        bn1r[j] = 1.f / sqrtf(var + BN_EPS);
    }
}

// ---------------- quantum phase macros (R20, unchanged) ----------------
#define SLA2(j) ((T << 4) | ((((j) ^ ((T >> 1) & 7))) << 1))
#define SLB(m)  (((T & 0xF0) << 4) | ((m) << 4) | ((T & 15) ^ ((m) & 14)))
#define SLC(m)  (((m) << 8) | (T ^ ((((T >> 5) & 7)) << 1)))

#define LDA(j, Ra, Rb) { v4f t_ = *(const v4f*)(xch + SLA2(j));                 \
    Ra = __builtin_shufflevector(t_, t_, 0, 1);                                 \
    Rb = __builtin_shufflevector(t_, t_, 2, 3); }
#define STA(j, Ra, Rb) { v4f t_ = __builtin_shufflevector(Ra, Rb, 0, 1, 2, 3);  \
    *(v4f*)(xch + SLA2(j)) = t_; }

#define LOADA do { LDA(0,s0,s1) LDA(1,s2,s3) LDA(2,s4,s5) LDA(3,s6,s7)          \
    LDA(4,s8,s9) LDA(5,s10,s11) LDA(6,s12,s13) LDA(7,s14,s15) } while (0)
#define STORA do { STA(0,s0,s1) STA(1,s2,s3) STA(2,s4,s5) STA(3,s6,s7)          \
    STA(4,s8,s9) STA(5,s10,s11) STA(6,s12,s13) STA(7,s14,s15) } while (0)

#define LOADW(SL) do {                                                          \
    s0=xch[SL(0)];  s1=xch[SL(1)];  s2=xch[SL(2)];  s3=xch[SL(3)];              \
    s4=xch[SL(4)];  s5=xch[SL(5)];  s6=xch[SL(6)];  s7=xch[SL(7)];              \
    s8=xch[SL(8)];  s9=xch[SL(9)];  s10=xch[SL(10)]; s11=xch[SL(11)];           \
    s12=xch[SL(12)]; s13=xch[SL(13)]; s14=xch[SL(14)]; s15=xch[SL(15)]; } while (0)
#define STORW(SL) do {                                                          \
    xch[SL(0)]=s0;  xch[SL(1)]=s1;  xch[SL(2)]=s2;  xch[SL(3)]=s3;              \
    xch[SL(4)]=s4;  xch[SL(5)]=s5;  xch[SL(6)]=s6;  xch[SL(7)]=s7;              \
    xch[SL(8)]=s8;  xch[SL(9)]=s9;  xch[SL(10)]=s10; xch[SL(11)]=s11;           \
    xch[SL(12)]=s12; xch[SL(13)]=s13; xch[SL(14)]=s14; xch[SL(15)]=s15; } while (0)

#define U_LOADP(uptr) const float* u_ = (uptr);                                  \
    v2f c00r = {u_[0], u_[0]}, c00i = {-u_[1], u_[1]};                           \
    v2f c01r = {u_[2], u_[2]}, c01i = {-u_[3], u_[3]};                           \
    v2f c10r = {u_[4], u_[4]}, c10i = {-u_[5], u_[5]};                           \
    v2f c11r = {u_[6], u_[6]}, c11i = {-u_[7], u_[7]};

#define U_LOADF(uptr) const float* f_ = (uptr);                                  \
    v2f d00r = {f_[0], f_[0]}, d00i = {-f_[1], f_[1]};                           \
    v2f d01r = {f_[2], f_[2]}, d01i = {-f_[3], f_[3]};                           \
    v2f d10r = {f_[4], f_[4]}, d10i = {-f_[5], f_[5]};                           \
    v2f d11r = {f_[6], f_[6]}, d11i = {-f_[7], f_[7]};

#define U_LOADSEL(uptr, gptr, cond) const float* u_ = (uptr);                    \
    const float* g_ = (gptr); int k_ = (cond);                                   \
    float e0_ = k_ ? g_[0] : u_[0], e1_ = k_ ? g_[1] : u_[1];                    \
    float e2_ = k_ ? g_[2] : u_[2], e3_ = k_ ? g_[3] : u_[3];                    \
    float e4_ = k_ ? g_[4] : u_[4], e5_ = k_ ? g_[5] : u_[5];                    \
    float e6_ = k_ ? g_[6] : u_[6], e7_ = k_ ? g_[7] : u_[7];                    \
    v2f c00r = {e0_, e0_}, c00i = {-e1_, e1_};                                   \
    v2f c01r = {e2_, e2_}, c01i = {-e3_, e3_};                                   \
    v2f c10r = {e4_, e4_}, c10i = {-e5_, e5_};                                   \
    v2f c11r = {e6_, e6_}, c11i = {-e7_, e7_};

#define U_PAIRP(A, B) { v2f a0 = A, a1 = B, a0s = SW2(a0), a1s = SW2(a1);        \
    A = a0*c00r + a0s*c00i + a1*c01r + a1s*c01i;                                 \
    B = a0*c10r + a0s*c10i + a1*c11r + a1s*c11i; }

#define U_PAIRF(A, B) { v2f a0 = A, a1 = B, a0s = SW2(a0), a1s = SW2(a1);        \
    A = a0*d00r + a0s*d00i + a1*d01r + a1s*d01i;                                 \
    B = a0*d10r + a0s*d10i + a1*d11r + a1s*d11i; }

#define APPLY_U_K3(uptr) do { U_LOADP(uptr)                                      \
    U_PAIRP(s0,s8) U_PAIRP(s1,s9) U_PAIRP(s2,s10) U_PAIRP(s3,s11)                \
    U_PAIRP(s4,s12) U_PAIRP(s5,s13) U_PAIRP(s6,s14) U_PAIRP(s7,s15) } while (0)

#define APPLY_USEL_K3(uptr, gptr, cond) do { U_LOADSEL(uptr, gptr, cond)         \
    U_PAIRP(s0,s8) U_PAIRP(s1,s9) U_PAIRP(s2,s10) U_PAIRP(s3,s11)                \
    U_PAIRP(s4,s12) U_PAIRP(s5,s13) U_PAIRP(s6,s14) U_PAIRP(s7,s15) } while (0)

#define APPLY_UF_K2(uP, uF) do { U_LOADP(uP) U_LOADF(uF)                         \
    U_PAIRP(s0,s4) U_PAIRP(s1,s5) U_PAIRP(s2,s6) U_PAIRP(s3,s7)                  \
    U_PAIRF(s8,s12) U_PAIRF(s9,s13) U_PAIRF(s10,s14) U_PAIRF(s11,s15) } while (0)
#define APPLY_UF_K1(uP, uF) do { U_LOADP(uP) U_LOADF(uF)                         \
    U_PAIRP(s0,s2) U_PAIRP(s1,s3) U_PAIRF(s4,s6) U_PAIRF(s5,s7)                  \
    U_PAIRP(s8,s10) U_PAIRP(s9,s11) U_PAIRF(s12,s14) U_PAIRF(s13,s15) } while (0)
#define APPLY_UF_K0(uP, uF) do { U_LOADP(uP) U_LOADF(uF)                         \
    U_PAIRP(s0,s1) U_PAIRF(s2,s3) U_PAIRP(s4,s5) U_PAIRF(s6,s7)                  \
    U_PAIRP(s8,s9) U_PAIRF(s10,s11) U_PAIRP(s12,s13) U_PAIRF(s14,s15) } while (0)

#define PRJ(S) ((S).x*(S).x + (S).y*(S).y)
#define WREDUCE(v) { v += __shfl_down(v,32,64); v += __shfl_down(v,16,64);       \
    v += __shfl_down(v,8,64); v += __shfl_down(v,4,64);                          \
    v += __shfl_down(v,2,64); v += __shfl_down(v,1,64); }

// quantum: one item = one batch row; 256 threads; xch = 32 KB LDS
__device__ __forceinline__ void quantum_item(int b, int T, v2f* __restrict__ xch,
        const float* __restrict__ enc,
        const float* __restrict__ bn1m, const float* __restrict__ bn1r,
        const float* __restrict__ g1, const float* __restrict__ b1,
        const float* __restrict__ gU, const float* __restrict__ gF,
        const float* __restrict__ gG, float* __restrict__ probs) {
    // ---- BN1 + tanh + qvec on 12 lanes, broadcast via LDS (R18) ----
    float* qv = (float*)xch;
    if (T < 16) {
        float h = 0.f;
        if (T < NQ) {
            h = tanhf(g1[T] * (enc[b * NQ + T] - bn1m[T]) * bn1r[T] + b1[T]);
        }
        float n2 = h * h;
        n2 += __shfl_xor(n2, 1, 16);
        n2 += __shfl_xor(n2, 2, 16);
        n2 += __shfl_xor(n2, 4, 16);
        n2 += __shfl_xor(n2, 8, 16);
        float norm = sqrtf(n2);
        bool  nz   = norm > 0.f;
        float rinv = 1.f / fmaxf(norm, 1e-30f);
        float a_   = nz ? h * rinv : h;
        float amp_ = fminf(fabsf(a_), 1.f);
        float qc   = sqrtf(fmaxf(1.f - amp_ * amp_, 0.f));
        float qs   = (a_ < 0.f) ? -amp_ : amp_;
        if (T < NQ) { qv[T * 2] = qc; qv[T * 2 + 1] = qs; }
    }
    __syncthreads();
    float qc0 = qv[0],  qs0 = qv[1],  qc1 = qv[2],  qs1 = qv[3];
    float qc2 = qv[4],  qs2 = qv[5],  qc3 = qv[6],  qs3 = qv[7];
    float qc4 = qv[8],  qs4 = qv[9],  qc5 = qv[10], qs5 = qv[11];
    float qc6 = qv[12], qs6 = qv[13], qc7 = qv[14], qs7 = qv[15];
    float qc8 = qv[16], qs8 = qv[17], qc9 = qv[18], qs9 = qv[19];
    float qc10 = qv[20], qs10 = qv[21], qc11 = qv[22], qs11 = qv[23];
    __syncthreads();

    v2f s0, s1, s2, s3, s4, s5, s6, s7, s8, s9, s10, s11, s12, s13, s14, s15;

    {
        float f = ((T>>7)&1 ? qs4 : qc4) * ((T>>6)&1 ? qs5 : qc5)
                * ((T>>5)&1 ? qs6 : qc6) * ((T>>4)&1 ? qs7 : qc7)
                * ((T>>3)&1 ? qs8 : qc8) * ((T>>2)&1 ? qs9 : qc9)
                * ((T>>1)&1 ? qs10 : qc10) * ((T>>0)&1 ? qs11 : qc11);
        float p0c = f * qc0,  p0s = f * qs0;
        float p00 = p0c*qc1, p01 = p0c*qs1, p10 = p0s*qc1, p11 = p0s*qs1;
        float q000 = p00*qc2, q001 = p00*qs2, q010 = p01*qc2, q011 = p01*qs2;
        float q100 = p10*qc2, q101 = p10*qs2, q110 = p11*qc2, q111 = p11*qs2;
        s0  = (v2f){q000*qc3, 0.f};  s1  = (v2f){q000*qs3, 0.f};
        s2  = (v2f){q001*qc3, 0.f};  s3  = (v2f){q001*qs3, 0.f};
        s4  = (v2f){q010*qc3, 0.f};  s5  = (v2f){q010*qs3, 0.f};
        s6  = (v2f){q011*qc3, 0.f};  s7  = (v2f){q011*qs3, 0.f};
        s8  = (v2f){q100*qc3, 0.f};  s9  = (v2f){q100*qs3, 0.f};
        s10 = (v2f){q101*qc3, 0.f};  s11 = (v2f){q101*qs3, 0.f};
        s12 = (v2f){q110*qc3, 0.f};  s13 = (v2f){q110*qs3, 0.f};
        s14 = (v2f){q111*qc3, 0.f};  s15 = (v2f){q111*qs3, 0.f};
        APPLY_U_K3(gU + 0 * 8);
        APPLY_UF_K2(gU + 1 * 8, gF + 0 * 8);
        APPLY_UF_K1(gU + 2 * 8, gF + 1 * 8);
        APPLY_UF_K0(gU + 3 * 8, gF + 2 * 8);
        STORW(SLC);
    }
    __syncthreads();

    #pragma unroll 1
    for (int l = 0; l < DEPTH; l++) {
        const float* UL = gU + l * 96;
        const float* FL = gF + l * 72;
        const float* GL = gG + l * 16;
        LOADW(SLB);
        APPLY_USEL_K3(UL + 4 * 8, GL + 0, T & 16);   // CRY3 ctrl = idx bit 8
        APPLY_UF_K2(UL + 5 * 8, FL + 3 * 8);
        APPLY_UF_K1(UL + 6 * 8, FL + 4 * 8);
        APPLY_UF_K0(UL + 7 * 8, FL + 5 * 8);
        STORW(SLB);
        __builtin_amdgcn_wave_barrier();             // B->A is wave-private
        LOADA;
        APPLY_USEL_K3(UL + 8 * 8, GL + 8, T & 1);    // CRY7 ctrl = idx bit 4
        APPLY_UF_K2(UL + 9 * 8, FL + 6 * 8);
        APPLY_UF_K1(UL + 10 * 8, FL + 7 * 8);
        APPLY_UF_K0(UL + 11 * 8, FL + 8 * 8);
        if (l < DEPTH - 1) {
            STORA;
            __syncthreads();
            const float* UN = gU + (l + 1) * 96;
            const float* FN = gF + (l + 1) * 72;
            LOADW(SLC);
            APPLY_U_K3(UN + 0 * 8);
            APPLY_UF_K2(UN + 1 * 8, FN + 0 * 8);
            APPLY_UF_K1(UN + 2 * 8, FN + 1 * 8);
            APPLY_UF_K0(UN + 3 * 8, FN + 2 * 8);
            STORW(SLC);
            __syncthreads();
        }
    }

    float p0 = PRJ(s0),  p1 = PRJ(s1),  p2 = PRJ(s2),  p3 = PRJ(s3);
    float p4 = PRJ(s4),  p5 = PRJ(s5),  p6 = PRJ(s6),  p7 = PRJ(s7);
    float p8 = PRJ(s8),  p9 = PRJ(s9),  p10 = PRJ(s10), p11 = PRJ(s11);
    float p12 = PRJ(s12), p13 = PRJ(s13), p14 = PRJ(s14), p15 = PRJ(s15);
    float tot = p0+p1+p2+p3+p4+p5+p6+p7+p8+p9+p10+p11+p12+p13+p14+p15;
    float r8  = p8+p9+p10+p11+p12+p13+p14+p15;
    float r9  = p4+p5+p6+p7+p12+p13+p14+p15;
    float r10 = p2+p3+p6+p7+p10+p11+p14+p15;
    float r11 = p1+p3+p5+p7+p9+p11+p13+p15;
    float r2 = (T & 32)  ? tot : 0.f;
    float r3 = (T & 16)  ? tot : 0.f;
    float r4 = (T & 8)   ? tot : 0.f;
    float r5 = (T & 4)   ? tot : 0.f;
    float r6 = (T & 2)   ? tot : 0.f;
    float r7 = (T & 1)   ? tot : 0.f;

    WREDUCE(tot)
    WREDUCE(r2) WREDUCE(r3) WREDUCE(r4) WREDUCE(r5) WREDUCE(r6) WREDUCE(r7)
    WREDUCE(r8) WREDUCE(r9) WREDUCE(r10) WREDUCE(r11)

    __syncthreads();
    float* red = (float*)xch;
    int lane = T & 63, w = T >> 6;
    if (lane == 0) {
        float* rr = red + w * NQ;
        rr[0] = (w & 2) ? tot : 0.f;
        rr[1] = (w & 1) ? tot : 0.f;
        rr[2]=r2; rr[3]=r3; rr[4]=r4; rr[5]=r5;
        rr[6]=r6; rr[7]=r7; rr[8]=r8; rr[9]=r9; rr[10]=r10; rr[11]=r11;
    }
    __syncthreads();
    if (T < NQ) probs[b * NQ + T] = red[T] + red[NQ + T] + red[2 * NQ + T] + red[3 * NQ + T];
}

// block-wide sum (256 threads), scr = 8 floats LDS
__device__ __forceinline__ float blockAllSum(float v, float* scr) {
    #pragma unroll
    for (int o = 32; o > 0; o >>= 1) v += __shfl_down(v, o, 64);
    int lane = threadIdx.x & 63, w = threadIdx.x >> 6;
    __syncthreads();
    if (lane == 0) scr[w] = v;
    __syncthreads();
    return scr[0] + scr[1] + scr[2] + scr[3];
}

// pcov: one item = one (q,q2) pair
__device__ __forceinline__ void pcov_item(int blk, int t, const float* __restrict__ probs,
                                          float* __restrict__ pmean, float* __restrict__ cov,
                                          float* __restrict__ scr) {
    int q = blk / NQ, q2 = blk % NQ;
    float sx = 0.f, sy = 0.f, sxy = 0.f;
    for (int b = t; b < BATCH; b += 256) {
        float xv = probs[b * NQ + q];
        float yv = probs[b * NQ + q2];
        sx += xv; sy += yv; sxy += xv * yv;
    }
    float SX  = blockAllSum(sx,  scr);
    float SY  = blockAllSum(sy,  scr);
    float SXY = blockAllSum(sxy, scr);
    if (t == 0) {
        float mx = SX / (float)BATCH, my = SY / (float)BATCH;
        cov[blk] = SXY / (float)BATCH - mx * my;
        if (q == q2) pmean[q] = mx;
    }
}

// final decode + BN2: grid-stride over 2048 items (2 rows each); wv/var/rstd hoisted
// per block (identical values/order per j -> same rounding as R20's per-row recompute).
__device__ __forceinline__ void final_phase(int start, int stride, int t,
        const float* __restrict__ probs, const float* __restrict__ pmean,
        const float* __restrict__ cov, const float* __restrict__ dw,
        const float* __restrict__ g2, const float* __restrict__ b2,
        float* __restrict__ out, float* __restrict__ cv,
        float* __restrict__ cp0, float* __restrict__ cp1) {
    if (t < NQ * NQ) cv[t] = cov[t];
    __syncthreads();
    float wv[NQ];
    #pragma unroll
    for (int q = 0; q < NQ; q++) wv[q] = dw[t * NQ + q];
    float var = 0.f;
    #pragma unroll
    for (int q = 0; q < NQ; q++) {
        float a = 0.f;
        #pragma unroll
        for (int q2 = 0; q2 < NQ; q2++) a += cv[q * NQ + q2] * wv[q2];
        var += wv[q] * a;
    }
    float rstd = 1.f / sqrtf(var + BN_EPS);
    float g2t = g2[t], b2t = b2[t];
    #pragma unroll 1
    for (int it = start; it < BATCH / 2; it += stride) {
        int b0 = it * 2;
        __syncthreads();
        if (t < NQ)                    cp0[t]      = probs[b0 * NQ + t]           - pmean[t];
        else if (t >= 64 && t < 64+NQ) cp1[t - 64] = probs[(b0+1) * NQ + (t - 64)] - pmean[t - 64];
        __syncthreads();
        float a0 = 0.f, a1 = 0.f;
        #pragma unroll
        for (int q = 0; q < NQ; q++) { a0 += cp0[q] * wv[q]; a1 += cp1[q] * wv[q]; }
        out[b0 * OUT_SZ + t]       = a0 * rstd * g2t + b2t;
        out[(b0 + 1) * OUT_SZ + t] = a1 * rstd * g2t + b2t;
    }
}

// ================= R23: the cooperative mega-kernel =================
__global__ void __launch_bounds__(256) k_mega(
        const float* __restrict__ x, const float* __restrict__ w,
        const float* __restrict__ bvec, const float* __restrict__ rot,
        const float* __restrict__ ent, const float* __restrict__ dw,
        const float* __restrict__ g1, const float* __restrict__ b1,
        const float* __restrict__ g2, const float* __restrict__ b2,
        float* __restrict__ enc, float* __restrict__ bn1m, float* __restrict__ bn1r,
        float* __restrict__ gU, float* __restrict__ gF, float* __restrict__ gG,
        float* __restrict__ probs, float* __restrict__ pmean, float* __restrict__ cov,
        float* __restrict__ out) {
    __shared__ __align__(16) v2f xch[NST];             // 32 KB, reused by every phase
    cg::grid_group grid = cg::this_grid();
    const int nb = (int)gridDim.x;
    const int T  = (int)threadIdx.x;

    // phase 1: encode (1024 row items) + gate prep (item 1024)
    #pragma unroll 1
    for (int it = blockIdx.x; it < 1025; it += nb) {
        if (it == 1024) gate_prep(T, rot, ent, gU, gF, gG);
        else            encode_rows(it, T, x, w, bvec, enc);
    }
    grid.sync();

    // phase 2: BN1 stats (12 items)
    #pragma unroll 1
    for (int j = blockIdx.x; j < NQ; j += nb)
        bnstats_item(j, T, enc, bn1m, bn1r, (float*)xch);
    grid.sync();

    // phase 3: quantum circuit (4096 items)
    #pragma unroll 1
    for (int b = blockIdx.x; b < BATCH; b += nb) {
        __syncthreads();                               // xch reuse across iterations
        quantum_item(b, T, xch, enc, bn1m, bn1r, g1, b1, gU, gF, gG, probs);
    }
    grid.sync();

    // phase 4: prob moments (144 items)
    #pragma unroll 1
    for (int blk = blockIdx.x; blk < NQ * NQ; blk += nb)
        pcov_item(blk, T, probs, pmean, cov, (float*)xch);
    grid.sync();

    // phase 5: decode + BN2 (2048 items)
    {
        float* cv  = (float*)xch;
        float* cp0 = (float*)xch + 160;
        float* cp1 = (float*)xch + 176;
        final_phase(blockIdx.x, nb, T, probs, pmean, cov, dw, g2, b2, out, cv, cp0, cp1);
    }
}

// ================= fallback kernels (proven R20 path; used only if coop rejected) ====
__global__ void k_encode_f(const float* __restrict__ x, const float* __restrict__ w,
                           const float* __restrict__ bvec, const float* __restrict__ rot,
                           const float* __restrict__ ent, float* __restrict__ enc,
                           float* __restrict__ gU, float* __restrict__ gF,
                           float* __restrict__ gG) {
    int it = blockIdx.x;
    if (it == 1024) gate_prep(threadIdx.x, rot, ent, gU, gF, gG);
    else            encode_rows(it, threadIdx.x, x, w, bvec, enc);
}

__global__ void k_bnstats_f(const float* __restrict__ enc, float* __restrict__ bn1m,
                            float* __restrict__ bn1r) {
    __shared__ float scr[16];
    bnstats_item(blockIdx.x, threadIdx.x, enc, bn1m, bn1r, scr);
}

__global__ void __launch_bounds__(256) k_quantum_f(const float* __restrict__ enc,
        const float* __restrict__ bn1m, const float* __restrict__ bn1r,
        const float* __restrict__ g1, const float* __restrict__ b1,
        const float* __restrict__ gU, const float* __restrict__ gF,
        const float* __restrict__ gG, float* __restrict__ probs) {
    __shared__ __align__(16) v2f xch[NST];
    quantum_item(blockIdx.x, threadIdx.x, xch, enc, bn1m, bn1r, g1, b1, gU, gF, gG, probs);
}

__global__ void k_pcov_f(const float* __restrict__ probs, float* __restrict__ pmean,
                         float* __restrict__ cov) {
    __shared__ float scr[8];
    pcov_item(blockIdx.x, threadIdx.x, probs, pmean, cov, scr);
}

__global__ void k_final_f(const float* __restrict__ probs, const float* __restrict__ pmean,
                          const float* __restrict__ cov, const float* __restrict__ dw,
                          const float* __restrict__ g2, const float* __restrict__ b2,
                          float* __restrict__ out) {
    __shared__ float buf[192];
    final_phase(blockIdx.x, gridDim.x, threadIdx.x, probs, pmean, cov, dw, g2, b2,
                out, buf, buf + 160, buf + 176);
}

extern "C" void kernel_launch(void* const* d_in, const int* in_sizes, int n_in,
                              void* d_out, int out_size, void* d_ws, size_t ws_size,
                              hipStream_t stream) {
    const float* x     = (const float*)d_in[0];
    const float* enc_w = (const float*)d_in[1];
    const float* enc_b = (const float*)d_in[2];
    const float* rot   = (const float*)d_in[3];
    const float* ent   = (const float*)d_in[4];
    const float* dec_w = (const float*)d_in[5];
    // d_in[6] = dec_b — cancels inside BN2
    const float* g1    = (const float*)d_in[7];
    const float* b1    = (const float*)d_in[8];
    const float* g2    = (const float*)d_in[9];
    const float* b2    = (const float*)d_in[10];

    float* ws    = (float*)d_ws;
    float* enc   = ws + OFF_ENC;
    float* bn1m  = ws + OFF_BN1M;
    float* bn1r  = ws + OFF_BN1R;
    float* gU    = ws + OFF_GU;
    float* gF    = ws + OFF_GF;
    float* gG    = ws + OFF_GG;
    float* prb   = ws + OFF_PROBS;
    float* pmean = ws + OFF_PMEAN;
    float* cov   = ws + OFF_COV;
    float* outp  = (float*)d_out;

    // co-residency-safe cooperative grid: occupancy (32KB LDS limits blocks/CU) x CUs,
    // capped at 1024 (4096/1024 -> perfectly balanced quantum rounds). Cached.
    static int g_grid = 0;
    if (g_grid == 0) {
        int nb = 0;
        if (hipOccupancyMaxActiveBlocksPerMultiprocessor(&nb, k_mega, 256, 0) != hipSuccess
            || nb < 1) nb = 2;
        int dev = 0;
        (void)hipGetDevice(&dev);
        int cus = 0;
        if (hipDeviceGetAttribute(&cus, hipDeviceAttributeMultiprocessorCount, dev) != hipSuccess
            || cus < 1) cus = 256;
        long g = (long)nb * (long)cus;
        g_grid = (g >= 1024) ? 1024 : (int)g;
    }

    void* kargs[] = {
        (void*)&x, (void*)&enc_w, (void*)&enc_b, (void*)&rot, (void*)&ent, (void*)&dec_w,
        (void*)&g1, (void*)&b1, (void*)&g2, (void*)&b2,
        (void*)&enc, (void*)&bn1m, (void*)&bn1r, (void*)&gU, (void*)&gF, (void*)&gG,
        (void*)&prb, (void*)&pmean, (void*)&cov, (void*)&outp
    };
    hipError_t err = hipLaunchCooperativeKernel(k_mega, dim3(g_grid), dim3(256),
                                                kargs, 0, stream);
    if (err != hipSuccess) {
        (void)hipGetLastError();               // clear; fall back to proven 5-kernel path
        hipLaunchKernelGGL(k_encode_f, dim3(1025), dim3(256), 0, stream,
                           x, enc_w, enc_b, rot, ent, enc, gU, gF, gG);
        hipLaunchKernelGGL(k_bnstats_f, dim3(NQ), dim3(256), 0, stream, enc, bn1m, bn1r);
        hipLaunchKernelGGL(k_quantum_f, dim3(BATCH), dim3(256), 0, stream,
                           enc, bn1m, bn1r, g1, b1, gU, gF, gG, prb);
        hipLaunchKernelGGL(k_pcov_f, dim3(NQ * NQ), dim3(256), 0, stream, prb, pmean, cov);
        hipLaunchKernelGGL(k_final_f, dim3(BATCH / 2), dim3(256), 0, stream,
                           prb, pmean, cov, dec_w, g2, b2, outp);
    }
}

// Round 8
// 197.330 us; speedup vs baseline: 2.0451x; 2.0451x over previous
//
#include <hip/hip_runtime.h>

#define BATCH   4096
#define IN_SZ   512
#define NQ      12
#define OUT_SZ  256
#define DEPTH   3
#define NST     4096   // 2^NQ
#define BN_EPS  1e-5f

// ---- ws layout (in floats) ----
#define OFF_ENC    0            // 4096*12 = 49152
#define OFF_BN1M   49152
#define OFF_BN1R   49168
#define OFF_GU     49184        // 288
#define OFF_GC     49472        // 66 (pad 96)
#define OFF_GF     49568        // DEPTH*9*8 = 216 (pad 224): fused Ry*U products (chain CRYs)
#define OFF_PROBS  49792        // 49152
#define OFF_PMEAN  98944
#define OFF_COV    98960        // 144
#define OFF_GG     99104        // DEPTH*2*8 = 48: Ry*U products for thread-bit CRYs (3,7)

typedef float v2f __attribute__((ext_vector_type(2)));
typedef float v4f __attribute__((ext_vector_type(4)));
#define SW2(a) __builtin_shufflevector(a, a, 1, 0)

// ================= K1: encode, wave-per-row (+ gates & fused products in block 1024) =========
__global__ void k_encode(const float* __restrict__ x, const float* __restrict__ w,
                         const float* __restrict__ bvec,
                         const float* __restrict__ rot, const float* __restrict__ ent,
                         float* __restrict__ enc, float* __restrict__ gU, float* __restrict__ gC,
                         float* __restrict__ gF, float* __restrict__ gG) {
    if (blockIdx.x == 1024) {
        int t = threadIdx.x;
        if (t < DEPTH * NQ) {
            float ax = rot[t * 3 + 0] * 0.5f;
            float ay = rot[t * 3 + 1] * 0.5f;
            float az = rot[t * 3 + 2] * 0.5f;
            float cx = cosf(ax), sx = sinf(ax);
            float cy = cosf(ay), sy = sinf(ay);
            float cz = cosf(az), sz = sinf(az);
            float m00r =  cy * cx, m00i =  sy * sx;
            float m01r = -sy * cx, m01i = -cy * sx;
            float m10r =  sy * cx, m10i = -cy * sx;
            float m11r =  cy * cx, m11i = -sy * sx;
            float* o = gU + t * 8;
            o[0] = cz * m00r + sz * m00i;  o[1] = cz * m00i - sz * m00r;
            o[2] = cz * m01r + sz * m01i;  o[3] = cz * m01i - sz * m01r;
            o[4] = cz * m10r - sz * m10i;  o[5] = cz * m10i + sz * m10r;
            o[6] = cz * m11r - sz * m11i;  o[7] = cz * m11i + sz * m11r;
        }
        if (t >= 64 && t - 64 < DEPTH * (NQ - 1)) {
            int i = t - 64;
            float th = ent[i] * 0.5f;
            gC[i * 2 + 0] = cosf(th);
            gC[i * 2 + 1] = sinf(th);
        }
        // fused products P = Ry(theta_c) * U_{c+1} for c in {0,1,2, 4,5,6, 8,9,10}
        if (t >= 128 && t - 128 < DEPTH * 9) {
            int i = t - 128;              // 0..26
            int l = i / 9, k = i % 9;
            int c = k + k / 3;            // 0,1,2,4,5,6,8,9,10
            int tq = c + 1;
            const float* rr = rot + (l * NQ + tq) * 3;
            float ax = rr[0] * 0.5f, ay = rr[1] * 0.5f, az = rr[2] * 0.5f;
            float cx = cosf(ax), sx = sinf(ax);
            float cy = cosf(ay), sy = sinf(ay);
            float cz = cosf(az), sz = sinf(az);
            float m00r =  cy * cx, m00i =  sy * sx;
            float m01r = -sy * cx, m01i = -cy * sx;
            float m10r =  sy * cx, m10i = -cy * sx;
            float m11r =  cy * cx, m11i = -sy * sx;
            float u0 = cz * m00r + sz * m00i, u1 = cz * m00i - sz * m00r;
            float u2 = cz * m01r + sz * m01i, u3 = cz * m01i - sz * m01r;
            float u4 = cz * m10r - sz * m10i, u5 = cz * m10i + sz * m10r;
            float u6 = cz * m11r - sz * m11i, u7 = cz * m11i + sz * m11r;
            float th = ent[l * (NQ - 1) + c] * 0.5f;
            float c_ = cosf(th), s_ = sinf(th);
            float* o = gF + i * 8;
            o[0] = c_ * u0 - s_ * u4;  o[1] = c_ * u1 - s_ * u5;
            o[2] = c_ * u2 - s_ * u6;  o[3] = c_ * u3 - s_ * u7;
            o[4] = s_ * u0 + c_ * u4;  o[5] = s_ * u1 + c_ * u5;
            o[6] = s_ * u2 + c_ * u6;  o[7] = s_ * u3 + c_ * u7;
        }
        // R20: fused products for the thread-bit CRYs: G = Ry(theta_c)*U_{c+1}, c in {3,7}
        if (t >= 160 && t - 160 < DEPTH * 2) {
            int i = t - 160;              // 0..5
            int l = i >> 1;
            int c = (i & 1) ? 7 : 3;
            int tq = c + 1;
            const float* rr = rot + (l * NQ + tq) * 3;
            float ax = rr[0] * 0.5f, ay = rr[1] * 0.5f, az = rr[2] * 0.5f;
            float cx = cosf(ax), sx = sinf(ax);
            float cy = cosf(ay), sy = sinf(ay);
            float cz = cosf(az), sz = sinf(az);
            float m00r =  cy * cx, m00i =  sy * sx;
            float m01r = -sy * cx, m01i = -cy * sx;
            float m10r =  sy * cx, m10i = -cy * sx;
            float m11r =  cy * cx, m11i = -sy * sx;
            float u0 = cz * m00r + sz * m00i, u1 = cz * m00i - sz * m00r;
            float u2 = cz * m01r + sz * m01i, u3 = cz * m01i - sz * m01r;
            float u4 = cz * m10r - sz * m10i, u5 = cz * m10i + sz * m10r;
            float u6 = cz * m11r - sz * m11i, u7 = cz * m11i + sz * m11r;
            float th = ent[l * (NQ - 1) + c] * 0.5f;
            float c_ = cosf(th), s_ = sinf(th);
            float* o = gG + (l * 2 + (i & 1)) * 8;
            o[0] = c_ * u0 - s_ * u4;  o[1] = c_ * u1 - s_ * u5;
            o[2] = c_ * u2 - s_ * u6;  o[3] = c_ * u3 - s_ * u7;
            o[4] = s_ * u0 + c_ * u4;  o[5] = s_ * u1 + c_ * u5;
            o[6] = s_ * u2 + c_ * u6;  o[7] = s_ * u3 + c_ * u7;
        }
        return;
    }
    int t = threadIdx.x;
    int wv = t >> 6, lane = t & 63;
    int row = blockIdx.x * 4 + wv;              // 1024 blocks x 4 waves = 4096 rows
    const float4* xr = (const float4*)(x + row * IN_SZ) + lane * 2;
    float4 xa = xr[0], xb = xr[1];
    float acc[NQ];
    #pragma unroll
    for (int q = 0; q < NQ; q++) {
        const float4* wr = (const float4*)(w + q * IN_SZ) + lane * 2;
        float4 wa = wr[0], wb = wr[1];
        float d = xa.x*wa.x + xa.y*wa.y + xa.z*wa.z + xa.w*wa.w
                + xb.x*wb.x + xb.y*wb.y + xb.z*wb.z + xb.w*wb.w;
        #pragma unroll
        for (int o = 32; o > 0; o >>= 1) d += __shfl_down(d, o, 64);
        acc[q] = d;
    }
    if (lane == 0) {
        float* er = enc + row * NQ;
        #pragma unroll
        for (int q = 0; q < NQ; q++) er[q] = acc[q] + bvec[q];
    }
}

// ================= K2: batchnorm1 stats — single pass, 1024 threads =================
__global__ void k_bnstats(const float* __restrict__ xm, float* __restrict__ mo,
                          float* __restrict__ ro) {
    __shared__ float scr[32];
    int j = blockIdx.x, t = threadIdx.x;
    float s = 0.f, s2 = 0.f;
    for (int b = t; b < BATCH; b += 1024) {
        float v = xm[b * NQ + j];
        s += v; s2 += v * v;
    }
    #pragma unroll
    for (int o = 32; o > 0; o >>= 1) { s += __shfl_down(s, o, 64); s2 += __shfl_down(s2, o, 64); }
    int lane = t & 63, w = t >> 6;
    if (lane == 0) { scr[w] = s; scr[16 + w] = s2; }
    __syncthreads();
    if (t == 0) {
        float S = 0.f, S2 = 0.f;
        #pragma unroll
        for (int i = 0; i < 16; i++) { S += scr[i]; S2 += scr[16 + i]; }
        float mean = S / (float)BATCH;
        float var  = S2 / (float)BATCH - mean * mean;
        mo[j] = mean;
        ro[j] = 1.f / sqrtf(var + BN_EPS);
    }
}

// ================= K3: quantum circuit — 3-pass schedule + CRY->U fusion =======
// Canonical amp index: qubit q at bit (11-q). Swizzle: slot = idx ^ (((idx>>5)&7)<<1).
// Window A: local bits 3..0 (qubits 8-11, b128); B: bits 7..4; C: bits 11..8.
// 3-pass layer schedule C->B->A by commutation (R14); CRY->U fusion (R15).
// R18: per-block qvec dedup (127.5 -> 117.4, VALU-issue removal == wall time).
// R20: CRY3/CRY7 defusion-by-selection (120.3 -> 113.9). BEST MEASURED: 199.4 total.
// LESSONS (measured): R10 — no offset hoisting / waves_per_eu (146->163).
// R12 — no 128B-padded atomics. R11 — no grid-scaled redundant stats math.
// R16 — no v2f coefficient tables (vector loads + vmcnt stalls, 126->170).
// R17 — no atomic moment tail (+11 us on k_quantum > one launch saved).
// R19 — no v_pk_*_f32 packed math: HALF-RATE on gfx950 (117.4->120.3).
// R21 — no serialized agent-scope atomic-load reduces (+84 us; atomics don't pipeline).
// R22 — hipMemsetAsync is a dispatch slot too (+8 us); slot count is the metric.
// R23 — NO cooperative grid.sync on MI355X: ~75 us/sync (8-XCD coherence + spin
//       traffic; FETCH 0.45->6.2 MB, VALUBusy 70->18%, total 199->430). The
//       5-kernel structure is optimal; its tail is real work + ~2-5 us/node gaps.
#define SLA2(j) ((T << 4) | ((((j) ^ ((T >> 1) & 7))) << 1))
#define SLB(m)  (((T & 0xF0) << 4) | ((m) << 4) | ((T & 15) ^ ((m) & 14)))
#define SLC(m)  (((m) << 8) | (T ^ ((((T >> 5) & 7)) << 1)))

#define LDA(j, Ra, Rb) { v4f t_ = *(const v4f*)(xch + SLA2(j));                 \
    Ra = __builtin_shufflevector(t_, t_, 0, 1);                                 \
    Rb = __builtin_shufflevector(t_, t_, 2, 3); }
#define STA(j, Ra, Rb) { v4f t_ = __builtin_shufflevector(Ra, Rb, 0, 1, 2, 3);  \
    *(v4f*)(xch + SLA2(j)) = t_; }

#define LOADA do { LDA(0,s0,s1) LDA(1,s2,s3) LDA(2,s4,s5) LDA(3,s6,s7)          \
    LDA(4,s8,s9) LDA(5,s10,s11) LDA(6,s12,s13) LDA(7,s14,s15) } while (0)
#define STORA do { STA(0,s0,s1) STA(1,s2,s3) STA(2,s4,s5) STA(3,s6,s7)          \
    STA(4,s8,s9) STA(5,s10,s11) STA(6,s12,s13) STA(7,s14,s15) } while (0)

#define LOADW(SL) do {                                                          \
    s0=xch[SL(0)];  s1=xch[SL(1)];  s2=xch[SL(2)];  s3=xch[SL(3)];              \
    s4=xch[SL(4)];  s5=xch[SL(5)];  s6=xch[SL(6)];  s7=xch[SL(7)];              \
    s8=xch[SL(8)];  s9=xch[SL(9)];  s10=xch[SL(10)]; s11=xch[SL(11)];           \
    s12=xch[SL(12)]; s13=xch[SL(13)]; s14=xch[SL(14)]; s15=xch[SL(15)]; } while (0)
#define STORW(SL) do {                                                          \
    xch[SL(0)]=s0;  xch[SL(1)]=s1;  xch[SL(2)]=s2;  xch[SL(3)]=s3;              \
    xch[SL(4)]=s4;  xch[SL(5)]=s5;  xch[SL(6)]=s6;  xch[SL(7)]=s7;              \
    xch[SL(8)]=s8;  xch[SL(9)]=s9;  xch[SL(10)]=s10; xch[SL(11)]=s11;           \
    xch[SL(12)]=s12; xch[SL(13)]=s13; xch[SL(14)]=s14; xch[SL(15)]=s15; } while (0)

#define U_LOADP(uptr) const float* u_ = (uptr);                                  \
    v2f c00r = {u_[0], u_[0]}, c00i = {-u_[1], u_[1]};                           \
    v2f c01r = {u_[2], u_[2]}, c01i = {-u_[3], u_[3]};                           \
    v2f c10r = {u_[4], u_[4]}, c10i = {-u_[5], u_[5]};                           \
    v2f c11r = {u_[6], u_[6]}, c11i = {-u_[7], u_[7]};

#define U_LOADF(uptr) const float* f_ = (uptr);                                  \
    v2f d00r = {f_[0], f_[0]}, d00i = {-f_[1], f_[1]};                           \
    v2f d01r = {f_[2], f_[2]}, d01i = {-f_[3], f_[3]};                           \
    v2f d10r = {f_[4], f_[4]}, d10i = {-f_[5], f_[5]};                           \
    v2f d11r = {f_[6], f_[6]}, d11i = {-f_[7], f_[7]};

// per-lane coefficient select between two wave-uniform 8-float sets (R20)
#define U_LOADSEL(uptr, gptr, cond) const float* u_ = (uptr);                    \
    const float* g_ = (gptr); int k_ = (cond);                                   \
    float e0_ = k_ ? g_[0] : u_[0], e1_ = k_ ? g_[1] : u_[1];                    \
    float e2_ = k_ ? g_[2] : u_[2], e3_ = k_ ? g_[3] : u_[3];                    \
    float e4_ = k_ ? g_[4] : u_[4], e5_ = k_ ? g_[5] : u_[5];                    \
    float e6_ = k_ ? g_[6] : u_[6], e7_ = k_ ? g_[7] : u_[7];                    \
    v2f c00r = {e0_, e0_}, c00i = {-e1_, e1_};                                   \
    v2f c01r = {e2_, e2_}, c01i = {-e3_, e3_};                                   \
    v2f c10r = {e4_, e4_}, c10i = {-e5_, e5_};                                   \
    v2f c11r = {e6_, e6_}, c11i = {-e7_, e7_};

#define U_PAIRP(A, B) { v2f a0 = A, a1 = B, a0s = SW2(a0), a1s = SW2(a1);        \
    A = a0*c00r + a0s*c00i + a1*c01r + a1s*c01i;                                 \
    B = a0*c10r + a0s*c10i + a1*c11r + a1s*c11i; }

#define U_PAIRF(A, B) { v2f a0 = A, a1 = B, a0s = SW2(a0), a1s = SW2(a1);        \
    A = a0*d00r + a0s*d00i + a1*d01r + a1s*d01i;                                 \
    B = a0*d10r + a0s*d10i + a1*d11r + a1s*d11i; }

#define APPLY_U_K3(uptr) do { U_LOADP(uptr)                                      \
    U_PAIRP(s0,s8) U_PAIRP(s1,s9) U_PAIRP(s2,s10) U_PAIRP(s3,s11)                \
    U_PAIRP(s4,s12) U_PAIRP(s5,s13) U_PAIRP(s6,s14) U_PAIRP(s7,s15) } while (0)

// R20: K3 apply with per-lane choice between U and fused Ry*U coefficient sets
#define APPLY_USEL_K3(uptr, gptr, cond) do { U_LOADSEL(uptr, gptr, cond)         \
    U_PAIRP(s0,s8) U_PAIRP(s1,s9) U_PAIRP(s2,s10) U_PAIRP(s3,s11)                \
    U_PAIRP(s4,s12) U_PAIRP(s5,s13) U_PAIRP(s6,s14) U_PAIRP(s7,s15) } while (0)

// fused: gate on bit2, coeff set selected by pair's bit3
#define APPLY_UF_K2(uP, uF) do { U_LOADP(uP) U_LOADF(uF)                         \
    U_PAIRP(s0,s4) U_PAIRP(s1,s5) U_PAIRP(s2,s6) U_PAIRP(s3,s7)                  \
    U_PAIRF(s8,s12) U_PAIRF(s9,s13) U_PAIRF(s10,s14) U_PAIRF(s11,s15) } while (0)
// fused: gate on bit1, selected by bit2
#define APPLY_UF_K1(uP, uF) do { U_LOADP(uP) U_LOADF(uF)                         \
    U_PAIRP(s0,s2) U_PAIRP(s1,s3) U_PAIRF(s4,s6) U_PAIRF(s5,s7)                  \
    U_PAIRP(s8,s10) U_PAIRP(s9,s11) U_PAIRF(s12,s14) U_PAIRF(s13,s15) } while (0)
// fused: gate on bit0, selected by bit1
#define APPLY_UF_K0(uP, uF) do { U_LOADP(uP) U_LOADF(uF)                         \
    U_PAIRP(s0,s1) U_PAIRF(s2,s3) U_PAIRP(s4,s5) U_PAIRF(s6,s7)                  \
    U_PAIRP(s8,s9) U_PAIRF(s10,s11) U_PAIRP(s12,s13) U_PAIRF(s14,s15) } while (0)

#define PRJ(S) ((S).x*(S).x + (S).y*(S).y)
#define WREDUCE(v) { v += __shfl_down(v,32,64); v += __shfl_down(v,16,64);       \
    v += __shfl_down(v,8,64); v += __shfl_down(v,4,64);                          \
    v += __shfl_down(v,2,64); v += __shfl_down(v,1,64); }

__launch_bounds__(256)
__global__ void k_quantum(const float* __restrict__ enc,
                          const float* __restrict__ bn1m, const float* __restrict__ bn1r,
                          const float* __restrict__ g1, const float* __restrict__ b1,
                          const float* __restrict__ gU, const float* __restrict__ gC,
                          const float* __restrict__ gF, const float* __restrict__ gG,
                          float* __restrict__ probs) {
    __shared__ __align__(16) v2f xch[NST];                        // exactly 32 KB

    int T = threadIdx.x, b = blockIdx.x;

    // ---- BN1 + tanh + qvec: block-uniform -> compute on 12 lanes, broadcast via LDS ----
    float* qv = (float*)xch;                  // first 24 floats of xch (state written later)
    if (T < 16) {
        float h = 0.f;
        if (T < NQ) {
            h = tanhf(g1[T] * (enc[b * NQ + T] - bn1m[T]) * bn1r[T] + b1[T]);
        }
        float n2 = h * h;
        n2 += __shfl_xor(n2, 1, 16);
        n2 += __shfl_xor(n2, 2, 16);
        n2 += __shfl_xor(n2, 4, 16);
        n2 += __shfl_xor(n2, 8, 16);
        float norm = sqrtf(n2);
        bool  nz   = norm > 0.f;
        float rinv = 1.f / fmaxf(norm, 1e-30f);
        float a_   = nz ? h * rinv : h;
        float amp_ = fminf(fabsf(a_), 1.f);
        float qc   = sqrtf(fmaxf(1.f - amp_ * amp_, 0.f));
        float qs   = (a_ < 0.f) ? -amp_ : amp_;
        if (T < NQ) { qv[T * 2] = qc; qv[T * 2 + 1] = qs; }
    }
    __syncthreads();
    float qc0 = qv[0],  qs0 = qv[1],  qc1 = qv[2],  qs1 = qv[3];
    float qc2 = qv[4],  qs2 = qv[5],  qc3 = qv[6],  qs3 = qv[7];
    float qc4 = qv[8],  qs4 = qv[9],  qc5 = qv[10], qs5 = qv[11];
    float qc6 = qv[12], qs6 = qv[13], qc7 = qv[14], qs7 = qv[15];
    float qc8 = qv[16], qs8 = qv[17], qc9 = qv[18], qs9 = qv[19];
    float qc10 = qv[20], qs10 = qv[21], qc11 = qv[22], qs11 = qv[23];
    __syncthreads();                          // qv reads done before STORW(SLC) overwrites

    v2f s0, s1, s2, s3, s4, s5, s6, s7, s8, s9, s10, s11, s12, s13, s14, s15;

    // ---- pass C, layer 0: init + U0 + fused(U1,CRY0) + fused(U2,CRY1) + fused(U3,CRY2) ----
    {
        float f = ((T>>7)&1 ? qs4 : qc4) * ((T>>6)&1 ? qs5 : qc5)
                * ((T>>5)&1 ? qs6 : qc6) * ((T>>4)&1 ? qs7 : qc7)
                * ((T>>3)&1 ? qs8 : qc8) * ((T>>2)&1 ? qs9 : qc9)
                * ((T>>1)&1 ? qs10 : qc10) * ((T>>0)&1 ? qs11 : qc11);
        // product tree (same left-assoc chains as before -> bit-exact, fewer muls)
        float p0c = f * qc0,  p0s = f * qs0;
        float p00 = p0c*qc1, p01 = p0c*qs1, p10 = p0s*qc1, p11 = p0s*qs1;
        float q000 = p00*qc2, q001 = p00*qs2, q010 = p01*qc2, q011 = p01*qs2;
        float q100 = p10*qc2, q101 = p10*qs2, q110 = p11*qc2, q111 = p11*qs2;
        s0  = (v2f){q000*qc3, 0.f};  s1  = (v2f){q000*qs3, 0.f};
        s2  = (v2f){q001*qc3, 0.f};  s3  = (v2f){q001*qs3, 0.f};
        s4  = (v2f){q010*qc3, 0.f};  s5  = (v2f){q010*qs3, 0.f};
        s6  = (v2f){q011*qc3, 0.f};  s7  = (v2f){q011*qs3, 0.f};
        s8  = (v2f){q100*qc3, 0.f};  s9  = (v2f){q100*qs3, 0.f};
        s10 = (v2f){q101*qc3, 0.f};  s11 = (v2f){q101*qs3, 0.f};
        s12 = (v2f){q110*qc3, 0.f};  s13 = (v2f){q110*qs3, 0.f};
        s14 = (v2f){q111*qc3, 0.f};  s15 = (v2f){q111*qs3, 0.f};
        APPLY_U_K3(gU + 0 * 8);
        APPLY_UF_K2(gU + 1 * 8, gF + 0 * 8);
        APPLY_UF_K1(gU + 2 * 8, gF + 1 * 8);
        APPLY_UF_K0(gU + 3 * 8, gF + 2 * 8);
        STORW(SLC);
    }
    __syncthreads();                          // C->B crosses waves

    #pragma unroll 1
    for (int l = 0; l < DEPTH; l++) {
        const float* UL = gU + l * 96;
        const float* FL = gF + l * 72;
        const float* GL = gG + l * 16;
        // ---- window B: fused(U4,CRY3 by lane bit) + fused(U5,CRY4) + fused(U6,CRY5) + fused(U7,CRY6) ----
        LOADW(SLB);
        APPLY_USEL_K3(UL + 4 * 8, GL + 0, T & 16);   // CRY3 ctrl = idx bit 8 -> lane bit
        APPLY_UF_K2(UL + 5 * 8, FL + 3 * 8);
        APPLY_UF_K1(UL + 6 * 8, FL + 4 * 8);
        APPLY_UF_K0(UL + 7 * 8, FL + 5 * 8);
        STORW(SLB);
        __builtin_amdgcn_wave_barrier();      // B->A is wave-private
        // ---- window A: fused(U8,CRY7 by lane bit) + fused(U9,CRY8) + fused(U10,CRY9) + fused(U11,CRY10) ----
        LOADA;
        APPLY_USEL_K3(UL + 8 * 8, GL + 8, T & 1);    // CRY7 ctrl = idx bit 4 -> lane bit
        APPLY_UF_K2(UL + 9 * 8, FL + 6 * 8);
        APPLY_UF_K1(UL + 10 * 8, FL + 7 * 8);
        APPLY_UF_K0(UL + 11 * 8, FL + 8 * 8);
        if (l < DEPTH - 1) {
            STORA;
            __syncthreads();                  // A->C crosses waves
            // ---- window C, layer l+1: U0 + fused CRY0-2 ----
            const float* UN = gU + (l + 1) * 96;
            const float* FN = gF + (l + 1) * 72;
            LOADW(SLC);
            APPLY_U_K3(UN + 0 * 8);
            APPLY_UF_K2(UN + 1 * 8, FN + 0 * 8);
            APPLY_UF_K1(UN + 2 * 8, FN + 1 * 8);
            APPLY_UF_K0(UN + 3 * 8, FN + 2 * 8);
            STORW(SLC);
            __syncthreads();                  // C->B crosses waves
        }
    }

    // ---- marginals from registers (window A: idx = T<<4 | m) ----
    float p0 = PRJ(s0),  p1 = PRJ(s1),  p2 = PRJ(s2),  p3 = PRJ(s3);
    float p4 = PRJ(s4),  p5 = PRJ(s5),  p6 = PRJ(s6),  p7 = PRJ(s7);
    float p8 = PRJ(s8),  p9 = PRJ(s9),  p10 = PRJ(s10), p11 = PRJ(s11);
    float p12 = PRJ(s12), p13 = PRJ(s13), p14 = PRJ(s14), p15 = PRJ(s15);
    float tot = p0+p1+p2+p3+p4+p5+p6+p7+p8+p9+p10+p11+p12+p13+p14+p15;
    float r8  = p8+p9+p10+p11+p12+p13+p14+p15;
    float r9  = p4+p5+p6+p7+p12+p13+p14+p15;
    float r10 = p2+p3+p6+p7+p10+p11+p14+p15;
    float r11 = p1+p3+p5+p7+p9+p11+p13+p15;
    // r0/r1 masks (T&128, T&64) are wave-uniform -> derive from one tot-reduce (bit-exact)
    float r2 = (T & 32)  ? tot : 0.f;
    float r3 = (T & 16)  ? tot : 0.f;
    float r4 = (T & 8)   ? tot : 0.f;
    float r5 = (T & 4)   ? tot : 0.f;
    float r6 = (T & 2)   ? tot : 0.f;
    float r7 = (T & 1)   ? tot : 0.f;

    WREDUCE(tot)
    WREDUCE(r2) WREDUCE(r3) WREDUCE(r4) WREDUCE(r5) WREDUCE(r6) WREDUCE(r7)
    WREDUCE(r8) WREDUCE(r9) WREDUCE(r10) WREDUCE(r11)

    __syncthreads();                     // xch no longer needed as state
    float* red = (float*)xch;
    int lane = T & 63, w = T >> 6;
    if (lane == 0) {
        float* rr = red + w * NQ;
        rr[0] = (w & 2) ? tot : 0.f;
        rr[1] = (w & 1) ? tot : 0.f;
        rr[2]=r2; rr[3]=r3; rr[4]=r4; rr[5]=r5;
        rr[6]=r6; rr[7]=r7; rr[8]=r8; rr[9]=r9; rr[10]=r10; rr[11]=r11;
    }
    __syncthreads();
    if (T < NQ) probs[b * NQ + T] = red[T] + red[NQ + T] + red[2 * NQ + T] + red[3 * NQ + T];
}

// ================= K4: prob moments -> pmean + cov (one pass, 1024 threads) =================
// R24: widened 256 -> 1024 threads (144 blocks cover only ~56% of CUs; kernel is
// latency-bound — 4 strided iterations instead of 16 with 4x the waves).
__global__ void k_pcov(const float* __restrict__ probs, float* __restrict__ pmean,
                       float* __restrict__ cov) {
    __shared__ float scr[48];
    int blk = blockIdx.x;             // 0..143
    int q = blk / NQ, q2 = blk % NQ;
    int t = threadIdx.x;
    float sx = 0.f, sy = 0.f, sxy = 0.f;
    for (int b = t; b < BATCH; b += 1024) {
        float xv = probs[b * NQ + q];
        float yv = probs[b * NQ + q2];
        sx += xv; sy += yv; sxy += xv * yv;
    }
    #pragma unroll
    for (int o = 32; o > 0; o >>= 1) {
        sx += __shfl_down(sx, o, 64);
        sy += __shfl_down(sy, o, 64);
        sxy += __shfl_down(sxy, o, 64);
    }
    int lane = t & 63, w = t >> 6;
    if (lane == 0) { scr[w] = sx; scr[16 + w] = sy; scr[32 + w] = sxy; }
    __syncthreads();
    if (t == 0) {
        float SX = 0.f, SY = 0.f, SXY = 0.f;
        #pragma unroll
        for (int i = 0; i < 16; i++) { SX += scr[i]; SY += scr[16 + i]; SXY += scr[32 + i]; }
        float mx = SX / (float)BATCH, my = SY / (float)BATCH;
        cov[blk] = SXY / (float)BATCH - mx * my;
        if (q == q2) pmean[q] = mx;
    }
}

// ================= K5: final decode + BN2, rstd folded in (2 rows per block) =================
// rstd = 1/sqrt(w^T cov w + eps) recomputed per block (156 FMA/thread) — removes the
// former 1-block k_rstd launch entirely; identical summation order -> bit-exact.
__global__ void k_final(const float* __restrict__ probs, const float* __restrict__ pmean,
                        const float* __restrict__ cov, const float* __restrict__ dw,
                        const float* __restrict__ g2, const float* __restrict__ b2,
                        float* __restrict__ out) {
    __shared__ float cp[2][NQ];
    __shared__ float cv[NQ * NQ];
    int b0 = blockIdx.x * 2;
    int t = threadIdx.x;
    int half = t >> 8, j = t & 255;
    if (t < NQ)                      cp[0][t]       = probs[b0 * NQ + t]        - pmean[t];
    else if (t >= 256 && t < 256+NQ) cp[1][t - 256] = probs[(b0+1) * NQ + t-256] - pmean[t - 256];
    if (t >= 32 && t < 32 + NQ * NQ) cv[t - 32] = cov[t - 32];
    __syncthreads();
    float wv[NQ];
    #pragma unroll
    for (int q = 0; q < NQ; q++) wv[q] = dw[j * NQ + q];
    float var = 0.f;
    #pragma unroll
    for (int q = 0; q < NQ; q++) {
        float a = 0.f;
        #pragma unroll
        for (int q2 = 0; q2 < NQ; q2++) a += cv[q * NQ + q2] * wv[q2];
        var += wv[q] * a;
    }
    float rstd = 1.f / sqrtf(var + BN_EPS);
    float acc = 0.f;
    #pragma unroll
    for (int q = 0; q < NQ; q++) acc += cp[half][q] * wv[q];
    out[(b0 + half) * OUT_SZ + j] = acc * rstd * g2[j] + b2[j];
}

extern "C" void kernel_launch(void* const* d_in, const int* in_sizes, int n_in,
                              void* d_out, int out_size, void* d_ws, size_t ws_size,
                              hipStream_t stream) {
    const float* x     = (const float*)d_in[0];
    const float* enc_w = (const float*)d_in[1];
    const float* enc_b = (const float*)d_in[2];
    const float* rot   = (const float*)d_in[3];
    const float* ent   = (const float*)d_in[4];
    const float* dec_w = (const float*)d_in[5];
    // d_in[6] = dec_b — cancels inside BN2
    const float* g1    = (const float*)d_in[7];
    const float* b1    = (const float*)d_in[8];
    const float* g2    = (const float*)d_in[9];
    const float* b2    = (const float*)d_in[10];

    float* ws    = (float*)d_ws;
    float* enc   = ws + OFF_ENC;
    float* bn1m  = ws + OFF_BN1M;
    float* bn1r  = ws + OFF_BN1R;
    float* gU    = ws + OFF_GU;
    float* gC    = ws + OFF_GC;
    float* gF    = ws + OFF_GF;
    float* gG    = ws + OFF_GG;
    float* prb   = ws + OFF_PROBS;
    float* pmean = ws + OFF_PMEAN;
    float* cov   = ws + OFF_COV;

    hipLaunchKernelGGL(k_encode, dim3(1025), dim3(256), 0, stream,
                       x, enc_w, enc_b, rot, ent, enc, gU, gC, gF, gG);
    hipLaunchKernelGGL(k_bnstats, dim3(NQ), dim3(1024), 0, stream, enc, bn1m, bn1r);
    hipLaunchKernelGGL(k_quantum, dim3(BATCH), dim3(256), 0, stream,
                       enc, bn1m, bn1r, g1, b1, gU, gC, gF, gG, prb);
    hipLaunchKernelGGL(k_pcov, dim3(NQ * NQ), dim3(1024), 0, stream, prb, pmean, cov);
    hipLaunchKernelGGL(k_final, dim3(BATCH / 2), dim3(512), 0, stream,
                       prb, pmean, cov, dec_w, g2, b2, (float*)d_out);
}

// Round 9
// 196.171 us; speedup vs baseline: 2.0572x; 1.0059x over previous
//
#include <hip/hip_runtime.h>

#define BATCH   4096
#define IN_SZ   512
#define NQ      12
#define OUT_SZ  256
#define DEPTH   3
#define NST     4096   // 2^NQ
#define BN_EPS  1e-5f

// ---- ws layout (in floats) ----
#define OFF_ENC    0            // 4096*12 = 49152
#define OFF_BN1M   49152
#define OFF_BN1R   49168
#define OFF_GU     49184        // 288
#define OFF_GC     49472        // 66 (pad 96)
#define OFF_GF     49568        // DEPTH*9*8 = 216 (pad 224): fused Ry*U products (chain CRYs)
#define OFF_PROBS  49792        // 49152
#define OFF_PMEAN  98944
#define OFF_COV    98960        // 144
#define OFF_GG     99104        // DEPTH*2*8 = 48: Ry*U products for thread-bit CRYs (3,7)

typedef float v2f __attribute__((ext_vector_type(2)));
typedef float v4f __attribute__((ext_vector_type(4)));
#define SW2(a) __builtin_shufflevector(a, a, 1, 0)

// ================= K1: encode, wave-per-row (+ gates & fused products in block 1024) =========
__global__ void k_encode(const float* __restrict__ x, const float* __restrict__ w,
                         const float* __restrict__ bvec,
                         const float* __restrict__ rot, const float* __restrict__ ent,
                         float* __restrict__ enc, float* __restrict__ gU, float* __restrict__ gC,
                         float* __restrict__ gF, float* __restrict__ gG) {
    if (blockIdx.x == 1024) {
        int t = threadIdx.x;
        if (t < DEPTH * NQ) {
            float ax = rot[t * 3 + 0] * 0.5f;
            float ay = rot[t * 3 + 1] * 0.5f;
            float az = rot[t * 3 + 2] * 0.5f;
            float cx = cosf(ax), sx = sinf(ax);
            float cy = cosf(ay), sy = sinf(ay);
            float cz = cosf(az), sz = sinf(az);
            float m00r =  cy * cx, m00i =  sy * sx;
            float m01r = -sy * cx, m01i = -cy * sx;
            float m10r =  sy * cx, m10i = -cy * sx;
            float m11r =  cy * cx, m11i = -sy * sx;
            float* o = gU + t * 8;
            o[0] = cz * m00r + sz * m00i;  o[1] = cz * m00i - sz * m00r;
            o[2] = cz * m01r + sz * m01i;  o[3] = cz * m01i - sz * m01r;
            o[4] = cz * m10r - sz * m10i;  o[5] = cz * m10i + sz * m10r;
            o[6] = cz * m11r - sz * m11i;  o[7] = cz * m11i + sz * m11r;
        }
        if (t >= 64 && t - 64 < DEPTH * (NQ - 1)) {
            int i = t - 64;
            float th = ent[i] * 0.5f;
            gC[i * 2 + 0] = cosf(th);
            gC[i * 2 + 1] = sinf(th);
        }
        // fused products P = Ry(theta_c) * U_{c+1} for c in {0,1,2, 4,5,6, 8,9,10}
        if (t >= 128 && t - 128 < DEPTH * 9) {
            int i = t - 128;              // 0..26
            int l = i / 9, k = i % 9;
            int c = k + k / 3;            // 0,1,2,4,5,6,8,9,10
            int tq = c + 1;
            const float* rr = rot + (l * NQ + tq) * 3;
            float ax = rr[0] * 0.5f, ay = rr[1] * 0.5f, az = rr[2] * 0.5f;
            float cx = cosf(ax), sx = sinf(ax);
            float cy = cosf(ay), sy = sinf(ay);
            float cz = cosf(az), sz = sinf(az);
            float m00r =  cy * cx, m00i =  sy * sx;
            float m01r = -sy * cx, m01i = -cy * sx;
            float m10r =  sy * cx, m10i = -cy * sx;
            float m11r =  cy * cx, m11i = -sy * sx;
            float u0 = cz * m00r + sz * m00i, u1 = cz * m00i - sz * m00r;
            float u2 = cz * m01r + sz * m01i, u3 = cz * m01i - sz * m01r;
            float u4 = cz * m10r - sz * m10i, u5 = cz * m10i + sz * m10r;
            float u6 = cz * m11r - sz * m11i, u7 = cz * m11i + sz * m11r;
            float th = ent[l * (NQ - 1) + c] * 0.5f;
            float c_ = cosf(th), s_ = sinf(th);
            float* o = gF + i * 8;
            o[0] = c_ * u0 - s_ * u4;  o[1] = c_ * u1 - s_ * u5;
            o[2] = c_ * u2 - s_ * u6;  o[3] = c_ * u3 - s_ * u7;
            o[4] = s_ * u0 + c_ * u4;  o[5] = s_ * u1 + c_ * u5;
            o[6] = s_ * u2 + c_ * u6;  o[7] = s_ * u3 + c_ * u7;
        }
        // R20: fused products for the thread-bit CRYs: G = Ry(theta_c)*U_{c+1}, c in {3,7}
        if (t >= 160 && t - 160 < DEPTH * 2) {
            int i = t - 160;              // 0..5
            int l = i >> 1;
            int c = (i & 1) ? 7 : 3;
            int tq = c + 1;
            const float* rr = rot + (l * NQ + tq) * 3;
            float ax = rr[0] * 0.5f, ay = rr[1] * 0.5f, az = rr[2] * 0.5f;
            float cx = cosf(ax), sx = sinf(ax);
            float cy = cosf(ay), sy = sinf(ay);
            float cz = cosf(az), sz = sinf(az);
            float m00r =  cy * cx, m00i =  sy * sx;
            float m01r = -sy * cx, m01i = -cy * sx;
            float m10r =  sy * cx, m10i = -cy * sx;
            float m11r =  cy * cx, m11i = -sy * sx;
            float u0 = cz * m00r + sz * m00i, u1 = cz * m00i - sz * m00r;
            float u2 = cz * m01r + sz * m01i, u3 = cz * m01i - sz * m01r;
            float u4 = cz * m10r - sz * m10i, u5 = cz * m10i + sz * m10r;
            float u6 = cz * m11r - sz * m11i, u7 = cz * m11i + sz * m11r;
            float th = ent[l * (NQ - 1) + c] * 0.5f;
            float c_ = cosf(th), s_ = sinf(th);
            float* o = gG + (l * 2 + (i & 1)) * 8;
            o[0] = c_ * u0 - s_ * u4;  o[1] = c_ * u1 - s_ * u5;
            o[2] = c_ * u2 - s_ * u6;  o[3] = c_ * u3 - s_ * u7;
            o[4] = s_ * u0 + c_ * u4;  o[5] = s_ * u1 + c_ * u5;
            o[6] = s_ * u2 + c_ * u6;  o[7] = s_ * u3 + c_ * u7;
        }
        return;
    }
    int t = threadIdx.x;
    int wv = t >> 6, lane = t & 63;
    int row = blockIdx.x * 4 + wv;              // 1024 blocks x 4 waves = 4096 rows
    const float4* xr = (const float4*)(x + row * IN_SZ) + lane * 2;
    float4 xa = xr[0], xb = xr[1];
    float acc[NQ];
    #pragma unroll
    for (int q = 0; q < NQ; q++) {
        const float4* wr = (const float4*)(w + q * IN_SZ) + lane * 2;
        float4 wa = wr[0], wb = wr[1];
        float d = xa.x*wa.x + xa.y*wa.y + xa.z*wa.z + xa.w*wa.w
                + xb.x*wb.x + xb.y*wb.y + xb.z*wb.z + xb.w*wb.w;
        #pragma unroll
        for (int o = 32; o > 0; o >>= 1) d += __shfl_down(d, o, 64);
        acc[q] = d;
    }
    if (lane == 0) {
        float* er = enc + row * NQ;
        #pragma unroll
        for (int q = 0; q < NQ; q++) er[q] = acc[q] + bvec[q];
    }
}

// ================= K2: batchnorm1 stats — single pass, 1024 threads =================
__global__ void k_bnstats(const float* __restrict__ xm, float* __restrict__ mo,
                          float* __restrict__ ro) {
    __shared__ float scr[32];
    int j = blockIdx.x, t = threadIdx.x;
    float s = 0.f, s2 = 0.f;
    for (int b = t; b < BATCH; b += 1024) {
        float v = xm[b * NQ + j];
        s += v; s2 += v * v;
    }
    #pragma unroll
    for (int o = 32; o > 0; o >>= 1) { s += __shfl_down(s, o, 64); s2 += __shfl_down(s2, o, 64); }
    int lane = t & 63, w = t >> 6;
    if (lane == 0) { scr[w] = s; scr[16 + w] = s2; }
    __syncthreads();
    if (t == 0) {
        float S = 0.f, S2 = 0.f;
        #pragma unroll
        for (int i = 0; i < 16; i++) { S += scr[i]; S2 += scr[16 + i]; }
        float mean = S / (float)BATCH;
        float var  = S2 / (float)BATCH - mean * mean;
        mo[j] = mean;
        ro[j] = 1.f / sqrtf(var + BN_EPS);
    }
}

// ================= K3: quantum circuit — 3-pass schedule + CRY->U fusion =======
// Canonical amp index: qubit q at bit (11-q). Swizzle: slot = idx ^ (((idx>>5)&7)<<1).
// Window A: local bits 3..0 (qubits 8-11, b128); B: bits 7..4; C: bits 11..8.
// 3-pass layer schedule C->B->A by commutation (R14); CRY->U fusion (R15).
// R18: per-block qvec dedup (127.5 -> 117.4, VALU-issue removal == wall time).
// R20: CRY3/CRY7 defusion-by-selection (120.3 -> 113.9). BEST: 197.3 total (R24).
// R25: s_setprio(1) around register-only gate-math clusters — blocks are
//      independent and phase-staggered on a CU (attn-like, m191 +4%); compute
//      bursts should win issue slots over co-resident waves' LDS/barrier phases.
//      Diagnostic: null => stall is barrier convoy, not issue arbitration.
// LESSONS (measured): R10 — no offset hoisting / waves_per_eu (146->163).
// R12 — no 128B-padded atomics. R11 — no grid-scaled redundant stats math.
// R16 — no v2f coefficient tables (vector loads + vmcnt stalls, 126->170).
// R17 — no atomic moment tail (+11 us on k_quantum > one launch saved).
// R19 — no v_pk_*_f32 packed math: HALF-RATE on gfx950 (117.4->120.3).
// R21 — no serialized agent-scope atomic-load reduces (+84 us; atomics don't pipeline).
// R22 — hipMemsetAsync is a dispatch slot too (+8 us); slot count is the metric.
// R23 — NO cooperative grid.sync on MI355X: ~75 us/sync (total 199->430).
#define SLA2(j) ((T << 4) | ((((j) ^ ((T >> 1) & 7))) << 1))
#define SLB(m)  (((T & 0xF0) << 4) | ((m) << 4) | ((T & 15) ^ ((m) & 14)))
#define SLC(m)  (((m) << 8) | (T ^ ((((T >> 5) & 7)) << 1)))

#define LDA(j, Ra, Rb) { v4f t_ = *(const v4f*)(xch + SLA2(j));                 \
    Ra = __builtin_shufflevector(t_, t_, 0, 1);                                 \
    Rb = __builtin_shufflevector(t_, t_, 2, 3); }
#define STA(j, Ra, Rb) { v4f t_ = __builtin_shufflevector(Ra, Rb, 0, 1, 2, 3);  \
    *(v4f*)(xch + SLA2(j)) = t_; }

#define LOADA do { LDA(0,s0,s1) LDA(1,s2,s3) LDA(2,s4,s5) LDA(3,s6,s7)          \
    LDA(4,s8,s9) LDA(5,s10,s11) LDA(6,s12,s13) LDA(7,s14,s15) } while (0)
#define STORA do { STA(0,s0,s1) STA(1,s2,s3) STA(2,s4,s5) STA(3,s6,s7)          \
    STA(4,s8,s9) STA(5,s10,s11) STA(6,s12,s13) STA(7,s14,s15) } while (0)

#define LOADW(SL) do {                                                          \
    s0=xch[SL(0)];  s1=xch[SL(1)];  s2=xch[SL(2)];  s3=xch[SL(3)];              \
    s4=xch[SL(4)];  s5=xch[SL(5)];  s6=xch[SL(6)];  s7=xch[SL(7)];              \
    s8=xch[SL(8)];  s9=xch[SL(9)];  s10=xch[SL(10)]; s11=xch[SL(11)];           \
    s12=xch[SL(12)]; s13=xch[SL(13)]; s14=xch[SL(14)]; s15=xch[SL(15)]; } while (0)
#define STORW(SL) do {                                                          \
    xch[SL(0)]=s0;  xch[SL(1)]=s1;  xch[SL(2)]=s2;  xch[SL(3)]=s3;              \
    xch[SL(4)]=s4;  xch[SL(5)]=s5;  xch[SL(6)]=s6;  xch[SL(7)]=s7;              \
    xch[SL(8)]=s8;  xch[SL(9)]=s9;  xch[SL(10)]=s10; xch[SL(11)]=s11;           \
    xch[SL(12)]=s12; xch[SL(13)]=s13; xch[SL(14)]=s14; xch[SL(15)]=s15; } while (0)

#define U_LOADP(uptr) const float* u_ = (uptr);                                  \
    v2f c00r = {u_[0], u_[0]}, c00i = {-u_[1], u_[1]};                           \
    v2f c01r = {u_[2], u_[2]}, c01i = {-u_[3], u_[3]};                           \
    v2f c10r = {u_[4], u_[4]}, c10i = {-u_[5], u_[5]};                           \
    v2f c11r = {u_[6], u_[6]}, c11i = {-u_[7], u_[7]};

#define U_LOADF(uptr) const float* f_ = (uptr);                                  \
    v2f d00r = {f_[0], f_[0]}, d00i = {-f_[1], f_[1]};                           \
    v2f d01r = {f_[2], f_[2]}, d01i = {-f_[3], f_[3]};                           \
    v2f d10r = {f_[4], f_[4]}, d10i = {-f_[5], f_[5]};                           \
    v2f d11r = {f_[6], f_[6]}, d11i = {-f_[7], f_[7]};

// per-lane coefficient select between two wave-uniform 8-float sets (R20)
#define U_LOADSEL(uptr, gptr, cond) const float* u_ = (uptr);                    \
    const float* g_ = (gptr); int k_ = (cond);                                   \
    float e0_ = k_ ? g_[0] : u_[0], e1_ = k_ ? g_[1] : u_[1];                    \
    float e2_ = k_ ? g_[2] : u_[2], e3_ = k_ ? g_[3] : u_[3];                    \
    float e4_ = k_ ? g_[4] : u_[4], e5_ = k_ ? g_[5] : u_[5];                    \
    float e6_ = k_ ? g_[6] : u_[6], e7_ = k_ ? g_[7] : u_[7];                    \
    v2f c00r = {e0_, e0_}, c00i = {-e1_, e1_};                                   \
    v2f c01r = {e2_, e2_}, c01i = {-e3_, e3_};                                   \
    v2f c10r = {e4_, e4_}, c10i = {-e5_, e5_};                                   \
    v2f c11r = {e6_, e6_}, c11i = {-e7_, e7_};

#define U_PAIRP(A, B) { v2f a0 = A, a1 = B, a0s = SW2(a0), a1s = SW2(a1);        \
    A = a0*c00r + a0s*c00i + a1*c01r + a1s*c01i;                                 \
    B = a0*c10r + a0s*c10i + a1*c11r + a1s*c11i; }

#define U_PAIRF(A, B) { v2f a0 = A, a1 = B, a0s = SW2(a0), a1s = SW2(a1);        \
    A = a0*d00r + a0s*d00i + a1*d01r + a1s*d01i;                                 \
    B = a0*d10r + a0s*d10i + a1*d11r + a1s*d11i; }

#define APPLY_U_K3(uptr) do { U_LOADP(uptr)                                      \
    U_PAIRP(s0,s8) U_PAIRP(s1,s9) U_PAIRP(s2,s10) U_PAIRP(s3,s11)                \
    U_PAIRP(s4,s12) U_PAIRP(s5,s13) U_PAIRP(s6,s14) U_PAIRP(s7,s15) } while (0)

// R20: K3 apply with per-lane choice between U and fused Ry*U coefficient sets
#define APPLY_USEL_K3(uptr, gptr, cond) do { U_LOADSEL(uptr, gptr, cond)         \
    U_PAIRP(s0,s8) U_PAIRP(s1,s9) U_PAIRP(s2,s10) U_PAIRP(s3,s11)                \
    U_PAIRP(s4,s12) U_PAIRP(s5,s13) U_PAIRP(s6,s14) U_PAIRP(s7,s15) } while (0)

// fused: gate on bit2, coeff set selected by pair's bit3
#define APPLY_UF_K2(uP, uF) do { U_LOADP(uP) U_LOADF(uF)                         \
    U_PAIRP(s0,s4) U_PAIRP(s1,s5) U_PAIRP(s2,s6) U_PAIRP(s3,s7)                  \
    U_PAIRF(s8,s12) U_PAIRF(s9,s13) U_PAIRF(s10,s14) U_PAIRF(s11,s15) } while (0)
// fused: gate on bit1, selected by bit2
#define APPLY_UF_K1(uP, uF) do { U_LOADP(uP) U_LOADF(uF)                         \
    U_PAIRP(s0,s2) U_PAIRP(s1,s3) U_PAIRF(s4,s6) U_PAIRF(s5,s7)                  \
    U_PAIRP(s8,s10) U_PAIRP(s9,s11) U_PAIRF(s12,s14) U_PAIRF(s13,s15) } while (0)
// fused: gate on bit0, selected by bit1
#define APPLY_UF_K0(uP, uF) do { U_LOADP(uP) U_LOADF(uF)                         \
    U_PAIRP(s0,s1) U_PAIRF(s2,s3) U_PAIRP(s4,s5) U_PAIRF(s6,s7)                  \
    U_PAIRP(s8,s9) U_PAIRF(s10,s11) U_PAIRP(s12,s13) U_PAIRF(s14,s15) } while (0)

#define PRJ(S) ((S).x*(S).x + (S).y*(S).y)
#define WREDUCE(v) { v += __shfl_down(v,32,64); v += __shfl_down(v,16,64);       \
    v += __shfl_down(v,8,64); v += __shfl_down(v,4,64);                          \
    v += __shfl_down(v,2,64); v += __shfl_down(v,1,64); }

#define PRIO_HI __builtin_amdgcn_s_setprio(1)
#define PRIO_LO __builtin_amdgcn_s_setprio(0)

__launch_bounds__(256)
__global__ void k_quantum(const float* __restrict__ enc,
                          const float* __restrict__ bn1m, const float* __restrict__ bn1r,
                          const float* __restrict__ g1, const float* __restrict__ b1,
                          const float* __restrict__ gU, const float* __restrict__ gC,
                          const float* __restrict__ gF, const float* __restrict__ gG,
                          float* __restrict__ probs) {
    __shared__ __align__(16) v2f xch[NST];                        // exactly 32 KB

    int T = threadIdx.x, b = blockIdx.x;

    // ---- BN1 + tanh + qvec: block-uniform -> compute on 12 lanes, broadcast via LDS ----
    float* qv = (float*)xch;                  // first 24 floats of xch (state written later)
    if (T < 16) {
        float h = 0.f;
        if (T < NQ) {
            h = tanhf(g1[T] * (enc[b * NQ + T] - bn1m[T]) * bn1r[T] + b1[T]);
        }
        float n2 = h * h;
        n2 += __shfl_xor(n2, 1, 16);
        n2 += __shfl_xor(n2, 2, 16);
        n2 += __shfl_xor(n2, 4, 16);
        n2 += __shfl_xor(n2, 8, 16);
        float norm = sqrtf(n2);
        bool  nz   = norm > 0.f;
        float rinv = 1.f / fmaxf(norm, 1e-30f);
        float a_   = nz ? h * rinv : h;
        float amp_ = fminf(fabsf(a_), 1.f);
        float qc   = sqrtf(fmaxf(1.f - amp_ * amp_, 0.f));
        float qs   = (a_ < 0.f) ? -amp_ : amp_;
        if (T < NQ) { qv[T * 2] = qc; qv[T * 2 + 1] = qs; }
    }
    __syncthreads();
    float qc0 = qv[0],  qs0 = qv[1],  qc1 = qv[2],  qs1 = qv[3];
    float qc2 = qv[4],  qs2 = qv[5],  qc3 = qv[6],  qs3 = qv[7];
    float qc4 = qv[8],  qs4 = qv[9],  qc5 = qv[10], qs5 = qv[11];
    float qc6 = qv[12], qs6 = qv[13], qc7 = qv[14], qs7 = qv[15];
    float qc8 = qv[16], qs8 = qv[17], qc9 = qv[18], qs9 = qv[19];
    float qc10 = qv[20], qs10 = qv[21], qc11 = qv[22], qs11 = qv[23];
    __syncthreads();                          // qv reads done before STORW(SLC) overwrites

    v2f s0, s1, s2, s3, s4, s5, s6, s7, s8, s9, s10, s11, s12, s13, s14, s15;

    // ---- pass C, layer 0: init + U0 + fused(U1,CRY0) + fused(U2,CRY1) + fused(U3,CRY2) ----
    {
        float f = ((T>>7)&1 ? qs4 : qc4) * ((T>>6)&1 ? qs5 : qc5)
                * ((T>>5)&1 ? qs6 : qc6) * ((T>>4)&1 ? qs7 : qc7)
                * ((T>>3)&1 ? qs8 : qc8) * ((T>>2)&1 ? qs9 : qc9)
                * ((T>>1)&1 ? qs10 : qc10) * ((T>>0)&1 ? qs11 : qc11);
        // product tree (same left-assoc chains as before -> bit-exact, fewer muls)
        float p0c = f * qc0,  p0s = f * qs0;
        float p00 = p0c*qc1, p01 = p0c*qs1, p10 = p0s*qc1, p11 = p0s*qs1;
        float q000 = p00*qc2, q001 = p00*qs2, q010 = p01*qc2, q011 = p01*qs2;
        float q100 = p10*qc2, q101 = p10*qs2, q110 = p11*qc2, q111 = p11*qs2;
        s0  = (v2f){q000*qc3, 0.f};  s1  = (v2f){q000*qs3, 0.f};
        s2  = (v2f){q001*qc3, 0.f};  s3  = (v2f){q001*qs3, 0.f};
        s4  = (v2f){q010*qc3, 0.f};  s5  = (v2f){q010*qs3, 0.f};
        s6  = (v2f){q011*qc3, 0.f};  s7  = (v2f){q011*qs3, 0.f};
        s8  = (v2f){q100*qc3, 0.f};  s9  = (v2f){q100*qs3, 0.f};
        s10 = (v2f){q101*qc3, 0.f};  s11 = (v2f){q101*qs3, 0.f};
        s12 = (v2f){q110*qc3, 0.f};  s13 = (v2f){q110*qs3, 0.f};
        s14 = (v2f){q111*qc3, 0.f};  s15 = (v2f){q111*qs3, 0.f};
        PRIO_HI;
        APPLY_U_K3(gU + 0 * 8);
        APPLY_UF_K2(gU + 1 * 8, gF + 0 * 8);
        APPLY_UF_K1(gU + 2 * 8, gF + 1 * 8);
        APPLY_UF_K0(gU + 3 * 8, gF + 2 * 8);
        PRIO_LO;
        STORW(SLC);
    }
    __syncthreads();                          // C->B crosses waves

    #pragma unroll 1
    for (int l = 0; l < DEPTH; l++) {
        const float* UL = gU + l * 96;
        const float* FL = gF + l * 72;
        const float* GL = gG + l * 16;
        // ---- window B: fused(U4,CRY3 by lane bit) + fused(U5,CRY4) + fused(U6,CRY5) + fused(U7,CRY6) ----
        LOADW(SLB);
        PRIO_HI;
        APPLY_USEL_K3(UL + 4 * 8, GL + 0, T & 16);   // CRY3 ctrl = idx bit 8 -> lane bit
        APPLY_UF_K2(UL + 5 * 8, FL + 3 * 8);
        APPLY_UF_K1(UL + 6 * 8, FL + 4 * 8);
        APPLY_UF_K0(UL + 7 * 8, FL + 5 * 8);
        PRIO_LO;
        STORW(SLB);
        __builtin_amdgcn_wave_barrier();      // B->A is wave-private
        // ---- window A: fused(U8,CRY7 by lane bit) + fused(U9,CRY8) + fused(U10,CRY9) + fused(U11,CRY10) ----
        LOADA;
        PRIO_HI;
        APPLY_USEL_K3(UL + 8 * 8, GL + 8, T & 1);    // CRY7 ctrl = idx bit 4 -> lane bit
        APPLY_UF_K2(UL + 9 * 8, FL + 6 * 8);
        APPLY_UF_K1(UL + 10 * 8, FL + 7 * 8);
        APPLY_UF_K0(UL + 11 * 8, FL + 8 * 8);
        PRIO_LO;
        if (l < DEPTH - 1) {
            STORA;
            __syncthreads();                  // A->C crosses waves
            // ---- window C, layer l+1: U0 + fused CRY0-2 ----
            const float* UN = gU + (l + 1) * 96;
            const float* FN = gF + (l + 1) * 72;
            LOADW(SLC);
            PRIO_HI;
            APPLY_U_K3(UN + 0 * 8);
            APPLY_UF_K2(UN + 1 * 8, FN + 0 * 8);
            APPLY_UF_K1(UN + 2 * 8, FN + 1 * 8);
            APPLY_UF_K0(UN + 3 * 8, FN + 2 * 8);
            PRIO_LO;
            STORW(SLC);
            __syncthreads();                  // C->B crosses waves
        }
    }

    // ---- marginals from registers (window A: idx = T<<4 | m) ----
    float p0 = PRJ(s0),  p1 = PRJ(s1),  p2 = PRJ(s2),  p3 = PRJ(s3);
    float p4 = PRJ(s4),  p5 = PRJ(s5),  p6 = PRJ(s6),  p7 = PRJ(s7);
    float p8 = PRJ(s8),  p9 = PRJ(s9),  p10 = PRJ(s10), p11 = PRJ(s11);
    float p12 = PRJ(s12), p13 = PRJ(s13), p14 = PRJ(s14), p15 = PRJ(s15);
    float tot = p0+p1+p2+p3+p4+p5+p6+p7+p8+p9+p10+p11+p12+p13+p14+p15;
    float r8  = p8+p9+p10+p11+p12+p13+p14+p15;
    float r9  = p4+p5+p6+p7+p12+p13+p14+p15;
    float r10 = p2+p3+p6+p7+p10+p11+p14+p15;
    float r11 = p1+p3+p5+p7+p9+p11+p13+p15;
    // r0/r1 masks (T&128, T&64) are wave-uniform -> derive from one tot-reduce (bit-exact)
    float r2 = (T & 32)  ? tot : 0.f;
    float r3 = (T & 16)  ? tot : 0.f;
    float r4 = (T & 8)   ? tot : 0.f;
    float r5 = (T & 4)   ? tot : 0.f;
    float r6 = (T & 2)   ? tot : 0.f;
    float r7 = (T & 1)   ? tot : 0.f;

    WREDUCE(tot)
    WREDUCE(r2) WREDUCE(r3) WREDUCE(r4) WREDUCE(r5) WREDUCE(r6) WREDUCE(r7)
    WREDUCE(r8) WREDUCE(r9) WREDUCE(r10) WREDUCE(r11)

    __syncthreads();                     // xch no longer needed as state
    float* red = (float*)xch;
    int lane = T & 63, w = T >> 6;
    if (lane == 0) {
        float* rr = red + w * NQ;
        rr[0] = (w & 2) ? tot : 0.f;
        rr[1] = (w & 1) ? tot : 0.f;
        rr[2]=r2; rr[3]=r3; rr[4]=r4; rr[5]=r5;
        rr[6]=r6; rr[7]=r7; rr[8]=r8; rr[9]=r9; rr[10]=r10; rr[11]=r11;
    }
    __syncthreads();
    if (T < NQ) probs[b * NQ + T] = red[T] + red[NQ + T] + red[2 * NQ + T] + red[3 * NQ + T];
}

// ================= K4: prob moments -> pmean + cov (one pass, 1024 threads) =================
// R24: widened 256 -> 1024 threads (144 blocks cover only ~56% of CUs; kernel is
// latency-bound — 4 strided iterations instead of 16 with 4x the waves).
__global__ void k_pcov(const float* __restrict__ probs, float* __restrict__ pmean,
                       float* __restrict__ cov) {
    __shared__ float scr[48];
    int blk = blockIdx.x;             // 0..143
    int q = blk / NQ, q2 = blk % NQ;
    int t = threadIdx.x;
    float sx = 0.f, sy = 0.f, sxy = 0.f;
    for (int b = t; b < BATCH; b += 1024) {
        float xv = probs[b * NQ + q];
        float yv = probs[b * NQ + q2];
        sx += xv; sy += yv; sxy += xv * yv;
    }
    #pragma unroll
    for (int o = 32; o > 0; o >>= 1) {
        sx += __shfl_down(sx, o, 64);
        sy += __shfl_down(sy, o, 64);
        sxy += __shfl_down(sxy, o, 64);
    }
    int lane = t & 63, w = t >> 6;
    if (lane == 0) { scr[w] = sx; scr[16 + w] = sy; scr[32 + w] = sxy; }
    __syncthreads();
    if (t == 0) {
        float SX = 0.f, SY = 0.f, SXY = 0.f;
        #pragma unroll
        for (int i = 0; i < 16; i++) { SX += scr[i]; SY += scr[16 + i]; SXY += scr[32 + i]; }
        float mx = SX / (float)BATCH, my = SY / (float)BATCH;
        cov[blk] = SXY / (float)BATCH - mx * my;
        if (q == q2) pmean[q] = mx;
    }
}

// ================= K5: final decode + BN2, rstd folded in (2 rows per block) =================
// rstd = 1/sqrt(w^T cov w + eps) recomputed per block (156 FMA/thread) — removes the
// former 1-block k_rstd launch entirely; identical summation order -> bit-exact.
__global__ void k_final(const float* __restrict__ probs, const float* __restrict__ pmean,
                        const float* __restrict__ cov, const float* __restrict__ dw,
                        const float* __restrict__ g2, const float* __restrict__ b2,
                        float* __restrict__ out) {
    __shared__ float cp[2][NQ];
    __shared__ float cv[NQ * NQ];
    int b0 = blockIdx.x * 2;
    int t = threadIdx.x;
    int half = t >> 8, j = t & 255;
    if (t < NQ)                      cp[0][t]       = probs[b0 * NQ + t]        - pmean[t];
    else if (t >= 256 && t < 256+NQ) cp[1][t - 256] = probs[(b0+1) * NQ + t-256] - pmean[t - 256];
    if (t >= 32 && t < 32 + NQ * NQ) cv[t - 32] = cov[t - 32];
    __syncthreads();
    float wv[NQ];
    #pragma unroll
    for (int q = 0; q < NQ; q++) wv[q] = dw[j * NQ + q];
    float var = 0.f;
    #pragma unroll
    for (int q = 0; q < NQ; q++) {
        float a = 0.f;
        #pragma unroll
        for (int q2 = 0; q2 < NQ; q2++) a += cv[q * NQ + q2] * wv[q2];
        var += wv[q] * a;
    }
    float rstd = 1.f / sqrtf(var + BN_EPS);
    float acc = 0.f;
    #pragma unroll
    for (int q = 0; q < NQ; q++) acc += cp[half][q] * wv[q];
    out[(b0 + half) * OUT_SZ + j] = acc * rstd * g2[j] + b2[j];
}

extern "C" void kernel_launch(void* const* d_in, const int* in_sizes, int n_in,
                              void* d_out, int out_size, void* d_ws, size_t ws_size,
                              hipStream_t stream) {
    const float* x     = (const float*)d_in[0];
    const float* enc_w = (const float*)d_in[1];
    const float* enc_b = (const float*)d_in[2];
    const float* rot   = (const float*)d_in[3];
    const float* ent   = (const float*)d_in[4];
    const float* dec_w = (const float*)d_in[5];
    // d_in[6] = dec_b — cancels inside BN2
    const float* g1    = (const float*)d_in[7];
    const float* b1    = (const float*)d_in[8];
    const float* g2    = (const float*)d_in[9];
    const float* b2    = (const float*)d_in[10];

    float* ws    = (float*)d_ws;
    float* enc   = ws + OFF_ENC;
    float* bn1m  = ws + OFF_BN1M;
    float* bn1r  = ws + OFF_BN1R;
    float* gU    = ws + OFF_GU;
    float* gC    = ws + OFF_GC;
    float* gF    = ws + OFF_GF;
    float* gG    = ws + OFF_GG;
    float* prb   = ws + OFF_PROBS;
    float* pmean = ws + OFF_PMEAN;
    float* cov   = ws + OFF_COV;

    hipLaunchKernelGGL(k_encode, dim3(1025), dim3(256), 0, stream,
                       x, enc_w, enc_b, rot, ent, enc, gU, gC, gF, gG);
    hipLaunchKernelGGL(k_bnstats, dim3(NQ), dim3(1024), 0, stream, enc, bn1m, bn1r);
    hipLaunchKernelGGL(k_quantum, dim3(BATCH), dim3(256), 0, stream,
                       enc, bn1m, bn1r, g1, b1, gU, gC, gF, gG, prb);
    hipLaunchKernelGGL(k_pcov, dim3(NQ * NQ), dim3(1024), 0, stream, prb, pmean, cov);
    hipLaunchKernelGGL(k_final, dim3(BATCH / 2), dim3(512), 0, stream,
                       prb, pmean, cov, dec_w, g2, b2, (float*)d_out);
}

// Round 10
// 192.275 us; speedup vs baseline: 2.0989x; 1.0203x over previous
//
#include <hip/hip_runtime.h>

#define BATCH   4096
#define IN_SZ   512
#define NQ      12
#define OUT_SZ  256
#define DEPTH   3
#define NST     4096   // 2^NQ
#define BN_EPS  1e-5f

// ---- ws layout (in floats) ----
#define OFF_ENC    0            // 4096*12 = 49152
#define OFF_BN1M   49152
#define OFF_BN1R   49168
#define OFF_GU     49184        // 288
#define OFF_GC     49472        // 66 (pad 96)
#define OFF_GF     49568        // DEPTH*9*8 = 216 (pad 224): fused Ry*U products (chain CRYs)
#define OFF_PROBS  49792        // 49152
#define OFF_PMEAN  98944
#define OFF_COV    98960        // 144
#define OFF_GG     99104        // DEPTH*2*8 = 48: Ry*U products for thread-bit CRYs (3,7)

typedef float v2f __attribute__((ext_vector_type(2)));
typedef float v4f __attribute__((ext_vector_type(4)));
#define SW2(a) __builtin_shufflevector(a, a, 1, 0)

// ================= K1: encode, wave-per-row (+ gates & fused products in block 1024) =========
__global__ void k_encode(const float* __restrict__ x, const float* __restrict__ w,
                         const float* __restrict__ bvec,
                         const float* __restrict__ rot, const float* __restrict__ ent,
                         float* __restrict__ enc, float* __restrict__ gU, float* __restrict__ gC,
                         float* __restrict__ gF, float* __restrict__ gG) {
    if (blockIdx.x == 1024) {
        int t = threadIdx.x;
        if (t < DEPTH * NQ) {
            float ax = rot[t * 3 + 0] * 0.5f;
            float ay = rot[t * 3 + 1] * 0.5f;
            float az = rot[t * 3 + 2] * 0.5f;
            float cx = cosf(ax), sx = sinf(ax);
            float cy = cosf(ay), sy = sinf(ay);
            float cz = cosf(az), sz = sinf(az);
            float m00r =  cy * cx, m00i =  sy * sx;
            float m01r = -sy * cx, m01i = -cy * sx;
            float m10r =  sy * cx, m10i = -cy * sx;
            float m11r =  cy * cx, m11i = -sy * sx;
            float* o = gU + t * 8;
            o[0] = cz * m00r + sz * m00i;  o[1] = cz * m00i - sz * m00r;
            o[2] = cz * m01r + sz * m01i;  o[3] = cz * m01i - sz * m01r;
            o[4] = cz * m10r - sz * m10i;  o[5] = cz * m10i + sz * m10r;
            o[6] = cz * m11r - sz * m11i;  o[7] = cz * m11i + sz * m11r;
        }
        if (t >= 64 && t - 64 < DEPTH * (NQ - 1)) {
            int i = t - 64;
            float th = ent[i] * 0.5f;
            gC[i * 2 + 0] = cosf(th);
            gC[i * 2 + 1] = sinf(th);
        }
        // fused products P = Ry(theta_c) * U_{c+1} for c in {0,1,2, 4,5,6, 8,9,10}
        if (t >= 128 && t - 128 < DEPTH * 9) {
            int i = t - 128;              // 0..26
            int l = i / 9, k = i % 9;
            int c = k + k / 3;            // 0,1,2,4,5,6,8,9,10
            int tq = c + 1;
            const float* rr = rot + (l * NQ + tq) * 3;
            float ax = rr[0] * 0.5f, ay = rr[1] * 0.5f, az = rr[2] * 0.5f;
            float cx = cosf(ax), sx = sinf(ax);
            float cy = cosf(ay), sy = sinf(ay);
            float cz = cosf(az), sz = sinf(az);
            float m00r =  cy * cx, m00i =  sy * sx;
            float m01r = -sy * cx, m01i = -cy * sx;
            float m10r =  sy * cx, m10i = -cy * sx;
            float m11r =  cy * cx, m11i = -sy * sx;
            float u0 = cz * m00r + sz * m00i, u1 = cz * m00i - sz * m00r;
            float u2 = cz * m01r + sz * m01i, u3 = cz * m01i - sz * m01r;
            float u4 = cz * m10r - sz * m10i, u5 = cz * m10i + sz * m10r;
            float u6 = cz * m11r - sz * m11i, u7 = cz * m11i + sz * m11r;
            float th = ent[l * (NQ - 1) + c] * 0.5f;
            float c_ = cosf(th), s_ = sinf(th);
            float* o = gF + i * 8;
            o[0] = c_ * u0 - s_ * u4;  o[1] = c_ * u1 - s_ * u5;
            o[2] = c_ * u2 - s_ * u6;  o[3] = c_ * u3 - s_ * u7;
            o[4] = s_ * u0 + c_ * u4;  o[5] = s_ * u1 + c_ * u5;
            o[6] = s_ * u2 + c_ * u6;  o[7] = s_ * u3 + c_ * u7;
        }
        // R20: fused products for the thread-bit CRYs: G = Ry(theta_c)*U_{c+1}, c in {3,7}
        if (t >= 160 && t - 160 < DEPTH * 2) {
            int i = t - 160;              // 0..5
            int l = i >> 1;
            int c = (i & 1) ? 7 : 3;
            int tq = c + 1;
            const float* rr = rot + (l * NQ + tq) * 3;
            float ax = rr[0] * 0.5f, ay = rr[1] * 0.5f, az = rr[2] * 0.5f;
            float cx = cosf(ax), sx = sinf(ax);
            float cy = cosf(ay), sy = sinf(ay);
            float cz = cosf(az), sz = sinf(az);
            float m00r =  cy * cx, m00i =  sy * sx;
            float m01r = -sy * cx, m01i = -cy * sx;
            float m10r =  sy * cx, m10i = -cy * sx;
            float m11r =  cy * cx, m11i = -sy * sx;
            float u0 = cz * m00r + sz * m00i, u1 = cz * m00i - sz * m00r;
            float u2 = cz * m01r + sz * m01i, u3 = cz * m01i - sz * m01r;
            float u4 = cz * m10r - sz * m10i, u5 = cz * m10i + sz * m10r;
            float u6 = cz * m11r - sz * m11i, u7 = cz * m11i + sz * m11r;
            float th = ent[l * (NQ - 1) + c] * 0.5f;
            float c_ = cosf(th), s_ = sinf(th);
            float* o = gG + (l * 2 + (i & 1)) * 8;
            o[0] = c_ * u0 - s_ * u4;  o[1] = c_ * u1 - s_ * u5;
            o[2] = c_ * u2 - s_ * u6;  o[3] = c_ * u3 - s_ * u7;
            o[4] = s_ * u0 + c_ * u4;  o[5] = s_ * u1 + c_ * u5;
            o[6] = s_ * u2 + c_ * u6;  o[7] = s_ * u3 + c_ * u7;
        }
        return;
    }
    int t = threadIdx.x;
    int wv = t >> 6, lane = t & 63;
    int row = blockIdx.x * 4 + wv;              // 1024 blocks x 4 waves = 4096 rows
    const float4* xr = (const float4*)(x + row * IN_SZ) + lane * 2;
    float4 xa = xr[0], xb = xr[1];
    float acc[NQ];
    #pragma unroll
    for (int q = 0; q < NQ; q++) {
        const float4* wr = (const float4*)(w + q * IN_SZ) + lane * 2;
        float4 wa = wr[0], wb = wr[1];
        float d = xa.x*wa.x + xa.y*wa.y + xa.z*wa.z + xa.w*wa.w
                + xb.x*wb.x + xb.y*wb.y + xb.z*wb.z + xb.w*wb.w;
        #pragma unroll
        for (int o = 32; o > 0; o >>= 1) d += __shfl_down(d, o, 64);
        acc[q] = d;
    }
    if (lane == 0) {
        float* er = enc + row * NQ;
        #pragma unroll
        for (int q = 0; q < NQ; q++) er[q] = acc[q] + bvec[q];
    }
}

// ================= K2: batchnorm1 stats — single pass, 1024 threads =================
__global__ void k_bnstats(const float* __restrict__ xm, float* __restrict__ mo,
                          float* __restrict__ ro) {
    __shared__ float scr[32];
    int j = blockIdx.x, t = threadIdx.x;
    float s = 0.f, s2 = 0.f;
    for (int b = t; b < BATCH; b += 1024) {
        float v = xm[b * NQ + j];
        s += v; s2 += v * v;
    }
    #pragma unroll
    for (int o = 32; o > 0; o >>= 1) { s += __shfl_down(s, o, 64); s2 += __shfl_down(s2, o, 64); }
    int lane = t & 63, w = t >> 6;
    if (lane == 0) { scr[w] = s; scr[16 + w] = s2; }
    __syncthreads();
    if (t == 0) {
        float S = 0.f, S2 = 0.f;
        #pragma unroll
        for (int i = 0; i < 16; i++) { S += scr[i]; S2 += scr[16 + i]; }
        float mean = S / (float)BATCH;
        float var  = S2 / (float)BATCH - mean * mean;
        mo[j] = mean;
        ro[j] = 1.f / sqrtf(var + BN_EPS);
    }
}

// ================= K3: quantum circuit — 3-pass schedule + CRY->U fusion =======
// Canonical amp index: qubit q at bit (11-q). Swizzle: slot = idx ^ (((idx>>5)&7)<<1).
// Window A: local bits 3..0 (qubits 8-11, b128); B: bits 7..4; C: bits 11..8.
// 3-pass layer schedule C->B->A by commutation (R14); CRY->U fusion (R15).
// R18: per-block qvec dedup (127.5 -> 117.4, VALU-issue removal == wall time).
// R20: CRY3/CRY7 defusion-by-selection (120.3 -> 113.9). BEST: 197.3 total (R24).
// LESSONS (measured): R10 — no offset hoisting / waves_per_eu (146->163).
// R12 — no 128B-padded atomics. R11 — no grid-scaled redundant stats math.
// R16 — no v2f coefficient tables (vector loads + vmcnt stalls, 126->170).
// R17 — no atomic moment tail (+11 us on k_quantum > one launch saved).
// R19 — no v_pk_*_f32 packed math: HALF-RATE on gfx950 (117.4->120.3).
// R21 — no serialized agent-scope atomic-load reduces (+84 us; atomics don't pipeline).
// R22 — hipMemsetAsync is a dispatch slot too (+8 us); slot count is the metric.
// R23 — NO cooperative grid.sync on MI355X: ~75 us/sync (total 199->430).
// R25 — no s_setprio: timed-neutral but profiled k_quantum 114->127 (VALUBusy
//       70->59%); stall is a barrier/LDS-latency convoy, not issue arbitration.
//       Remaining k_quantum lever = half-LDS occupancy rewrite (needs 3 buffers +
//       4x barriers — declined at zero absmax margin).
#define SLA2(j) ((T << 4) | ((((j) ^ ((T >> 1) & 7))) << 1))
#define SLB(m)  (((T & 0xF0) << 4) | ((m) << 4) | ((T & 15) ^ ((m) & 14)))
#define SLC(m)  (((m) << 8) | (T ^ ((((T >> 5) & 7)) << 1)))

#define LDA(j, Ra, Rb) { v4f t_ = *(const v4f*)(xch + SLA2(j));                 \
    Ra = __builtin_shufflevector(t_, t_, 0, 1);                                 \
    Rb = __builtin_shufflevector(t_, t_, 2, 3); }
#define STA(j, Ra, Rb) { v4f t_ = __builtin_shufflevector(Ra, Rb, 0, 1, 2, 3);  \
    *(v4f*)(xch + SLA2(j)) = t_; }

#define LOADA do { LDA(0,s0,s1) LDA(1,s2,s3) LDA(2,s4,s5) LDA(3,s6,s7)          \
    LDA(4,s8,s9) LDA(5,s10,s11) LDA(6,s12,s13) LDA(7,s14,s15) } while (0)
#define STORA do { STA(0,s0,s1) STA(1,s2,s3) STA(2,s4,s5) STA(3,s6,s7)          \
    STA(4,s8,s9) STA(5,s10,s11) STA(6,s12,s13) STA(7,s14,s15) } while (0)

#define LOADW(SL) do {                                                          \
    s0=xch[SL(0)];  s1=xch[SL(1)];  s2=xch[SL(2)];  s3=xch[SL(3)];              \
    s4=xch[SL(4)];  s5=xch[SL(5)];  s6=xch[SL(6)];  s7=xch[SL(7)];              \
    s8=xch[SL(8)];  s9=xch[SL(9)];  s10=xch[SL(10)]; s11=xch[SL(11)];           \
    s12=xch[SL(12)]; s13=xch[SL(13)]; s14=xch[SL(14)]; s15=xch[SL(15)]; } while (0)
#define STORW(SL) do {                                                          \
    xch[SL(0)]=s0;  xch[SL(1)]=s1;  xch[SL(2)]=s2;  xch[SL(3)]=s3;              \
    xch[SL(4)]=s4;  xch[SL(5)]=s5;  xch[SL(6)]=s6;  xch[SL(7)]=s7;              \
    xch[SL(8)]=s8;  xch[SL(9)]=s9;  xch[SL(10)]=s10; xch[SL(11)]=s11;           \
    xch[SL(12)]=s12; xch[SL(13)]=s13; xch[SL(14)]=s14; xch[SL(15)]=s15; } while (0)

#define U_LOADP(uptr) const float* u_ = (uptr);                                  \
    v2f c00r = {u_[0], u_[0]}, c00i = {-u_[1], u_[1]};                           \
    v2f c01r = {u_[2], u_[2]}, c01i = {-u_[3], u_[3]};                           \
    v2f c10r = {u_[4], u_[4]}, c10i = {-u_[5], u_[5]};                           \
    v2f c11r = {u_[6], u_[6]}, c11i = {-u_[7], u_[7]};

#define U_LOADF(uptr) const float* f_ = (uptr);                                  \
    v2f d00r = {f_[0], f_[0]}, d00i = {-f_[1], f_[1]};                           \
    v2f d01r = {f_[2], f_[2]}, d01i = {-f_[3], f_[3]};                           \
    v2f d10r = {f_[4], f_[4]}, d10i = {-f_[5], f_[5]};                           \
    v2f d11r = {f_[6], f_[6]}, d11i = {-f_[7], f_[7]};

// per-lane coefficient select between two wave-uniform 8-float sets (R20)
#define U_LOADSEL(uptr, gptr, cond) const float* u_ = (uptr);                    \
    const float* g_ = (gptr); int k_ = (cond);                                   \
    float e0_ = k_ ? g_[0] : u_[0], e1_ = k_ ? g_[1] : u_[1];                    \
    float e2_ = k_ ? g_[2] : u_[2], e3_ = k_ ? g_[3] : u_[3];                    \
    float e4_ = k_ ? g_[4] : u_[4], e5_ = k_ ? g_[5] : u_[5];                    \
    float e6_ = k_ ? g_[6] : u_[6], e7_ = k_ ? g_[7] : u_[7];                    \
    v2f c00r = {e0_, e0_}, c00i = {-e1_, e1_};                                   \
    v2f c01r = {e2_, e2_}, c01i = {-e3_, e3_};                                   \
    v2f c10r = {e4_, e4_}, c10i = {-e5_, e5_};                                   \
    v2f c11r = {e6_, e6_}, c11i = {-e7_, e7_};

#define U_PAIRP(A, B) { v2f a0 = A, a1 = B, a0s = SW2(a0), a1s = SW2(a1);        \
    A = a0*c00r + a0s*c00i + a1*c01r + a1s*c01i;                                 \
    B = a0*c10r + a0s*c10i + a1*c11r + a1s*c11i; }

#define U_PAIRF(A, B) { v2f a0 = A, a1 = B, a0s = SW2(a0), a1s = SW2(a1);        \
    A = a0*d00r + a0s*d00i + a1*d01r + a1s*d01i;                                 \
    B = a0*d10r + a0s*d10i + a1*d11r + a1s*d11i; }

#define APPLY_U_K3(uptr) do { U_LOADP(uptr)                                      \
    U_PAIRP(s0,s8) U_PAIRP(s1,s9) U_PAIRP(s2,s10) U_PAIRP(s3,s11)                \
    U_PAIRP(s4,s12) U_PAIRP(s5,s13) U_PAIRP(s6,s14) U_PAIRP(s7,s15) } while (0)

// R20: K3 apply with per-lane choice between U and fused Ry*U coefficient sets
#define APPLY_USEL_K3(uptr, gptr, cond) do { U_LOADSEL(uptr, gptr, cond)         \
    U_PAIRP(s0,s8) U_PAIRP(s1,s9) U_PAIRP(s2,s10) U_PAIRP(s3,s11)                \
    U_PAIRP(s4,s12) U_PAIRP(s5,s13) U_PAIRP(s6,s14) U_PAIRP(s7,s15) } while (0)

// fused: gate on bit2, coeff set selected by pair's bit3
#define APPLY_UF_K2(uP, uF) do { U_LOADP(uP) U_LOADF(uF)                         \
    U_PAIRP(s0,s4) U_PAIRP(s1,s5) U_PAIRP(s2,s6) U_PAIRP(s3,s7)                  \
    U_PAIRF(s8,s12) U_PAIRF(s9,s13) U_PAIRF(s10,s14) U_PAIRF(s11,s15) } while (0)
// fused: gate on bit1, selected by bit2
#define APPLY_UF_K1(uP, uF) do { U_LOADP(uP) U_LOADF(uF)                         \
    U_PAIRP(s0,s2) U_PAIRP(s1,s3) U_PAIRF(s4,s6) U_PAIRF(s5,s7)                  \
    U_PAIRP(s8,s10) U_PAIRP(s9,s11) U_PAIRF(s12,s14) U_PAIRF(s13,s15) } while (0)
// fused: gate on bit0, selected by bit1
#define APPLY_UF_K0(uP, uF) do { U_LOADP(uP) U_LOADF(uF)                         \
    U_PAIRP(s0,s1) U_PAIRF(s2,s3) U_PAIRP(s4,s5) U_PAIRF(s6,s7)                  \
    U_PAIRP(s8,s9) U_PAIRF(s10,s11) U_PAIRP(s12,s13) U_PAIRF(s14,s15) } while (0)

#define PRJ(S) ((S).x*(S).x + (S).y*(S).y)
#define WREDUCE(v) { v += __shfl_down(v,32,64); v += __shfl_down(v,16,64);       \
    v += __shfl_down(v,8,64); v += __shfl_down(v,4,64);                          \
    v += __shfl_down(v,2,64); v += __shfl_down(v,1,64); }

__launch_bounds__(256)
__global__ void k_quantum(const float* __restrict__ enc,
                          const float* __restrict__ bn1m, const float* __restrict__ bn1r,
                          const float* __restrict__ g1, const float* __restrict__ b1,
                          const float* __restrict__ gU, const float* __restrict__ gC,
                          const float* __restrict__ gF, const float* __restrict__ gG,
                          float* __restrict__ probs) {
    __shared__ __align__(16) v2f xch[NST];                        // exactly 32 KB

    int T = threadIdx.x, b = blockIdx.x;

    // ---- BN1 + tanh + qvec: block-uniform -> compute on 12 lanes, broadcast via LDS ----
    float* qv = (float*)xch;                  // first 24 floats of xch (state written later)
    if (T < 16) {
        float h = 0.f;
        if (T < NQ) {
            h = tanhf(g1[T] * (enc[b * NQ + T] - bn1m[T]) * bn1r[T] + b1[T]);
        }
        float n2 = h * h;
        n2 += __shfl_xor(n2, 1, 16);
        n2 += __shfl_xor(n2, 2, 16);
        n2 += __shfl_xor(n2, 4, 16);
        n2 += __shfl_xor(n2, 8, 16);
        float norm = sqrtf(n2);
        bool  nz   = norm > 0.f;
        float rinv = 1.f / fmaxf(norm, 1e-30f);
        float a_   = nz ? h * rinv : h;
        float amp_ = fminf(fabsf(a_), 1.f);
        float qc   = sqrtf(fmaxf(1.f - amp_ * amp_, 0.f));
        float qs   = (a_ < 0.f) ? -amp_ : amp_;
        if (T < NQ) { qv[T * 2] = qc; qv[T * 2 + 1] = qs; }
    }
    __syncthreads();
    float qc0 = qv[0],  qs0 = qv[1],  qc1 = qv[2],  qs1 = qv[3];
    float qc2 = qv[4],  qs2 = qv[5],  qc3 = qv[6],  qs3 = qv[7];
    float qc4 = qv[8],  qs4 = qv[9],  qc5 = qv[10], qs5 = qv[11];
    float qc6 = qv[12], qs6 = qv[13], qc7 = qv[14], qs7 = qv[15];
    float qc8 = qv[16], qs8 = qv[17], qc9 = qv[18], qs9 = qv[19];
    float qc10 = qv[20], qs10 = qv[21], qc11 = qv[22], qs11 = qv[23];
    __syncthreads();                          // qv reads done before STORW(SLC) overwrites

    v2f s0, s1, s2, s3, s4, s5, s6, s7, s8, s9, s10, s11, s12, s13, s14, s15;

    // ---- pass C, layer 0: init + U0 + fused(U1,CRY0) + fused(U2,CRY1) + fused(U3,CRY2) ----
    {
        float f = ((T>>7)&1 ? qs4 : qc4) * ((T>>6)&1 ? qs5 : qc5)
                * ((T>>5)&1 ? qs6 : qc6) * ((T>>4)&1 ? qs7 : qc7)
                * ((T>>3)&1 ? qs8 : qc8) * ((T>>2)&1 ? qs9 : qc9)
                * ((T>>1)&1 ? qs10 : qc10) * ((T>>0)&1 ? qs11 : qc11);
        // product tree (same left-assoc chains as before -> bit-exact, fewer muls)
        float p0c = f * qc0,  p0s = f * qs0;
        float p00 = p0c*qc1, p01 = p0c*qs1, p10 = p0s*qc1, p11 = p0s*qs1;
        float q000 = p00*qc2, q001 = p00*qs2, q010 = p01*qc2, q011 = p01*qs2;
        float q100 = p10*qc2, q101 = p10*qs2, q110 = p11*qc2, q111 = p11*qs2;
        s0  = (v2f){q000*qc3, 0.f};  s1  = (v2f){q000*qs3, 0.f};
        s2  = (v2f){q001*qc3, 0.f};  s3  = (v2f){q001*qs3, 0.f};
        s4  = (v2f){q010*qc3, 0.f};  s5  = (v2f){q010*qs3, 0.f};
        s6  = (v2f){q011*qc3, 0.f};  s7  = (v2f){q011*qs3, 0.f};
        s8  = (v2f){q100*qc3, 0.f};  s9  = (v2f){q100*qs3, 0.f};
        s10 = (v2f){q101*qc3, 0.f};  s11 = (v2f){q101*qs3, 0.f};
        s12 = (v2f){q110*qc3, 0.f};  s13 = (v2f){q110*qs3, 0.f};
        s14 = (v2f){q111*qc3, 0.f};  s15 = (v2f){q111*qs3, 0.f};
        APPLY_U_K3(gU + 0 * 8);
        APPLY_UF_K2(gU + 1 * 8, gF + 0 * 8);
        APPLY_UF_K1(gU + 2 * 8, gF + 1 * 8);
        APPLY_UF_K0(gU + 3 * 8, gF + 2 * 8);
        STORW(SLC);
    }
    __syncthreads();                          // C->B crosses waves

    #pragma unroll 1
    for (int l = 0; l < DEPTH; l++) {
        const float* UL = gU + l * 96;
        const float* FL = gF + l * 72;
        const float* GL = gG + l * 16;
        // ---- window B: fused(U4,CRY3 by lane bit) + fused(U5,CRY4) + fused(U6,CRY5) + fused(U7,CRY6) ----
        LOADW(SLB);
        APPLY_USEL_K3(UL + 4 * 8, GL + 0, T & 16);   // CRY3 ctrl = idx bit 8 -> lane bit
        APPLY_UF_K2(UL + 5 * 8, FL + 3 * 8);
        APPLY_UF_K1(UL + 6 * 8, FL + 4 * 8);
        APPLY_UF_K0(UL + 7 * 8, FL + 5 * 8);
        STORW(SLB);
        __builtin_amdgcn_wave_barrier();      // B->A is wave-private
        // ---- window A: fused(U8,CRY7 by lane bit) + fused(U9,CRY8) + fused(U10,CRY9) + fused(U11,CRY10) ----
        LOADA;
        APPLY_USEL_K3(UL + 8 * 8, GL + 8, T & 1);    // CRY7 ctrl = idx bit 4 -> lane bit
        APPLY_UF_K2(UL + 9 * 8, FL + 6 * 8);
        APPLY_UF_K1(UL + 10 * 8, FL + 7 * 8);
        APPLY_UF_K0(UL + 11 * 8, FL + 8 * 8);
        if (l < DEPTH - 1) {
            STORA;
            __syncthreads();                  // A->C crosses waves
            // ---- window C, layer l+1: U0 + fused CRY0-2 ----
            const float* UN = gU + (l + 1) * 96;
            const float* FN = gF + (l + 1) * 72;
            LOADW(SLC);
            APPLY_U_K3(UN + 0 * 8);
            APPLY_UF_K2(UN + 1 * 8, FN + 0 * 8);
            APPLY_UF_K1(UN + 2 * 8, FN + 1 * 8);
            APPLY_UF_K0(UN + 3 * 8, FN + 2 * 8);
            STORW(SLC);
            __syncthreads();                  // C->B crosses waves
        }
    }

    // ---- marginals from registers (window A: idx = T<<4 | m) ----
    float p0 = PRJ(s0),  p1 = PRJ(s1),  p2 = PRJ(s2),  p3 = PRJ(s3);
    float p4 = PRJ(s4),  p5 = PRJ(s5),  p6 = PRJ(s6),  p7 = PRJ(s7);
    float p8 = PRJ(s8),  p9 = PRJ(s9),  p10 = PRJ(s10), p11 = PRJ(s11);
    float p12 = PRJ(s12), p13 = PRJ(s13), p14 = PRJ(s14), p15 = PRJ(s15);
    float tot = p0+p1+p2+p3+p4+p5+p6+p7+p8+p9+p10+p11+p12+p13+p14+p15;
    float r8  = p8+p9+p10+p11+p12+p13+p14+p15;
    float r9  = p4+p5+p6+p7+p12+p13+p14+p15;
    float r10 = p2+p3+p6+p7+p10+p11+p14+p15;
    float r11 = p1+p3+p5+p7+p9+p11+p13+p15;
    // r0/r1 masks (T&128, T&64) are wave-uniform -> derive from one tot-reduce (bit-exact)
    float r2 = (T & 32)  ? tot : 0.f;
    float r3 = (T & 16)  ? tot : 0.f;
    float r4 = (T & 8)   ? tot : 0.f;
    float r5 = (T & 4)   ? tot : 0.f;
    float r6 = (T & 2)   ? tot : 0.f;
    float r7 = (T & 1)   ? tot : 0.f;

    WREDUCE(tot)
    WREDUCE(r2) WREDUCE(r3) WREDUCE(r4) WREDUCE(r5) WREDUCE(r6) WREDUCE(r7)
    WREDUCE(r8) WREDUCE(r9) WREDUCE(r10) WREDUCE(r11)

    __syncthreads();                     // xch no longer needed as state
    float* red = (float*)xch;
    int lane = T & 63, w = T >> 6;
    if (lane == 0) {
        float* rr = red + w * NQ;
        rr[0] = (w & 2) ? tot : 0.f;
        rr[1] = (w & 1) ? tot : 0.f;
        rr[2]=r2; rr[3]=r3; rr[4]=r4; rr[5]=r5;
        rr[6]=r6; rr[7]=r7; rr[8]=r8; rr[9]=r9; rr[10]=r10; rr[11]=r11;
    }
    __syncthreads();
    if (T < NQ) probs[b * NQ + T] = red[T] + red[NQ + T] + red[2 * NQ + T] + red[3 * NQ + T];
}

// ================= K4: prob moments -> pmean + cov (one pass, 1024 threads) =================
// R24: widened 256 -> 1024 threads (144 blocks cover only ~56% of CUs; kernel is
// latency-bound — 4 strided iterations instead of 16 with 4x the waves).
__global__ void k_pcov(const float* __restrict__ probs, float* __restrict__ pmean,
                       float* __restrict__ cov) {
    __shared__ float scr[48];
    int blk = blockIdx.x;             // 0..143
    int q = blk / NQ, q2 = blk % NQ;
    int t = threadIdx.x;
    float sx = 0.f, sy = 0.f, sxy = 0.f;
    for (int b = t; b < BATCH; b += 1024) {
        float xv = probs[b * NQ + q];
        float yv = probs[b * NQ + q2];
        sx += xv; sy += yv; sxy += xv * yv;
    }
    #pragma unroll
    for (int o = 32; o > 0; o >>= 1) {
        sx += __shfl_down(sx, o, 64);
        sy += __shfl_down(sy, o, 64);
        sxy += __shfl_down(sxy, o, 64);
    }
    int lane = t & 63, w = t >> 6;
    if (lane == 0) { scr[w] = sx; scr[16 + w] = sy; scr[32 + w] = sxy; }
    __syncthreads();
    if (t == 0) {
        float SX = 0.f, SY = 0.f, SXY = 0.f;
        #pragma unroll
        for (int i = 0; i < 16; i++) { SX += scr[i]; SY += scr[16 + i]; SXY += scr[32 + i]; }
        float mx = SX / (float)BATCH, my = SY / (float)BATCH;
        cov[blk] = SXY / (float)BATCH - mx * my;
        if (q == q2) pmean[q] = mx;
    }
}

// ================= K5: final decode + BN2, rstd amortized over 16 rows/block =================
// R26: rstd (156 FMA/thread, the dominant cost) + cv/wv/g2/b2 loads computed ONCE
// per block, then 8 x 2-row iterations. Per-j math/order identical to R24 ->
// bit-exact. Grid 256 blocks x 512 threads (8 waves/CU for this tiny kernel).
__global__ void k_final(const float* __restrict__ probs, const float* __restrict__ pmean,
                        const float* __restrict__ cov, const float* __restrict__ dw,
                        const float* __restrict__ g2, const float* __restrict__ b2,
                        float* __restrict__ out) {
    __shared__ float cp[2][NQ];
    __shared__ float cv[NQ * NQ];
    int t = threadIdx.x;
    int half = t >> 8, j = t & 255;
    if (t < NQ * NQ) cv[t] = cov[t];
    __syncthreads();
    float wv[NQ];
    #pragma unroll
    for (int q = 0; q < NQ; q++) wv[q] = dw[j * NQ + q];
    float var = 0.f;
    #pragma unroll
    for (int q = 0; q < NQ; q++) {
        float a = 0.f;
        #pragma unroll
        for (int q2 = 0; q2 < NQ; q2++) a += cv[q * NQ + q2] * wv[q2];
        var += wv[q] * a;
    }
    float rstd = 1.f / sqrtf(var + BN_EPS);
    float g2t = g2[j], b2t = b2[j];
    #pragma unroll 1
    for (int it = 0; it < 8; it++) {
        int b0 = blockIdx.x * 16 + it * 2;
        __syncthreads();                 // previous iteration's cp reads done
        if (t < NQ)                      cp[0][t]       = probs[b0 * NQ + t]        - pmean[t];
        else if (t >= 256 && t < 256+NQ) cp[1][t - 256] = probs[(b0+1) * NQ + t-256] - pmean[t - 256];
        __syncthreads();
        float acc = 0.f;
        #pragma unroll
        for (int q = 0; q < NQ; q++) acc += cp[half][q] * wv[q];
        out[(b0 + half) * OUT_SZ + j] = acc * rstd * g2t + b2t;
    }
}

extern "C" void kernel_launch(void* const* d_in, const int* in_sizes, int n_in,
                              void* d_out, int out_size, void* d_ws, size_t ws_size,
                              hipStream_t stream) {
    const float* x     = (const float*)d_in[0];
    const float* enc_w = (const float*)d_in[1];
    const float* enc_b = (const float*)d_in[2];
    const float* rot   = (const float*)d_in[3];
    const float* ent   = (const float*)d_in[4];
    const float* dec_w = (const float*)d_in[5];
    // d_in[6] = dec_b — cancels inside BN2
    const float* g1    = (const float*)d_in[7];
    const float* b1    = (const float*)d_in[8];
    const float* g2    = (const float*)d_in[9];
    const float* b2    = (const float*)d_in[10];

    float* ws    = (float*)d_ws;
    float* enc   = ws + OFF_ENC;
    float* bn1m  = ws + OFF_BN1M;
    float* bn1r  = ws + OFF_BN1R;
    float* gU    = ws + OFF_GU;
    float* gC    = ws + OFF_GC;
    float* gF    = ws + OFF_GF;
    float* gG    = ws + OFF_GG;
    float* prb   = ws + OFF_PROBS;
    float* pmean = ws + OFF_PMEAN;
    float* cov   = ws + OFF_COV;

    hipLaunchKernelGGL(k_encode, dim3(1025), dim3(256), 0, stream,
                       x, enc_w, enc_b, rot, ent, enc, gU, gC, gF, gG);
    hipLaunchKernelGGL(k_bnstats, dim3(NQ), dim3(1024), 0, stream, enc, bn1m, bn1r);
    hipLaunchKernelGGL(k_quantum, dim3(BATCH), dim3(256), 0, stream,
                       enc, bn1m, bn1r, g1, b1, gU, gC, gF, gG, prb);
    hipLaunchKernelGGL(k_pcov, dim3(NQ * NQ), dim3(1024), 0, stream, prb, pmean, cov);
    hipLaunchKernelGGL(k_final, dim3(BATCH / 16), dim3(512), 0, stream,
                       prb, pmean, cov, dec_w, g2, b2, (float*)d_out);
}

// Round 11
// 190.904 us; speedup vs baseline: 2.1139x; 1.0072x over previous
//
#include <hip/hip_runtime.h>

#define BATCH   4096
#define IN_SZ   512
#define NQ      12
#define OUT_SZ  256
#define DEPTH   3
#define NST     4096   // 2^NQ
#define BN_EPS  1e-5f

// ---- ws layout (in floats) ----
#define OFF_ENC    0            // 4096*12 = 49152
#define OFF_BN1M   49152
#define OFF_BN1R   49168
#define OFF_GU     49184        // 288
#define OFF_GC     49472        // 66 (pad 96)
#define OFF_GF     49568        // DEPTH*9*8 = 216 (pad 224): fused Ry*U products (chain CRYs)
#define OFF_PROBS  49792        // 49152
#define OFF_PMEAN  98944
#define OFF_COV    98960        // 144
#define OFF_GG     99104        // DEPTH*2*8 = 48: Ry*U products for thread-bit CRYs (3,7)

typedef float v2f __attribute__((ext_vector_type(2)));
typedef float v4f __attribute__((ext_vector_type(4)));
#define SW2(a) __builtin_shufflevector(a, a, 1, 0)

// ================= K1: encode, wave-per-row (+ gates & fused products in block 1024) =========
__global__ void k_encode(const float* __restrict__ x, const float* __restrict__ w,
                         const float* __restrict__ bvec,
                         const float* __restrict__ rot, const float* __restrict__ ent,
                         float* __restrict__ enc, float* __restrict__ gU, float* __restrict__ gC,
                         float* __restrict__ gF, float* __restrict__ gG) {
    if (blockIdx.x == 1024) {
        int t = threadIdx.x;
        if (t < DEPTH * NQ) {
            float ax = rot[t * 3 + 0] * 0.5f;
            float ay = rot[t * 3 + 1] * 0.5f;
            float az = rot[t * 3 + 2] * 0.5f;
            float cx = cosf(ax), sx = sinf(ax);
            float cy = cosf(ay), sy = sinf(ay);
            float cz = cosf(az), sz = sinf(az);
            float m00r =  cy * cx, m00i =  sy * sx;
            float m01r = -sy * cx, m01i = -cy * sx;
            float m10r =  sy * cx, m10i = -cy * sx;
            float m11r =  cy * cx, m11i = -sy * sx;
            float* o = gU + t * 8;
            o[0] = cz * m00r + sz * m00i;  o[1] = cz * m00i - sz * m00r;
            o[2] = cz * m01r + sz * m01i;  o[3] = cz * m01i - sz * m01r;
            o[4] = cz * m10r - sz * m10i;  o[5] = cz * m10i + sz * m10r;
            o[6] = cz * m11r - sz * m11i;  o[7] = cz * m11i + sz * m11r;
        }
        if (t >= 64 && t - 64 < DEPTH * (NQ - 1)) {
            int i = t - 64;
            float th = ent[i] * 0.5f;
            gC[i * 2 + 0] = cosf(th);
            gC[i * 2 + 1] = sinf(th);
        }
        // fused products P = Ry(theta_c) * U_{c+1} for c in {0,1,2, 4,5,6, 8,9,10}
        if (t >= 128 && t - 128 < DEPTH * 9) {
            int i = t - 128;              // 0..26
            int l = i / 9, k = i % 9;
            int c = k + k / 3;            // 0,1,2,4,5,6,8,9,10
            int tq = c + 1;
            const float* rr = rot + (l * NQ + tq) * 3;
            float ax = rr[0] * 0.5f, ay = rr[1] * 0.5f, az = rr[2] * 0.5f;
            float cx = cosf(ax), sx = sinf(ax);
            float cy = cosf(ay), sy = sinf(ay);
            float cz = cosf(az), sz = sinf(az);
            float m00r =  cy * cx, m00i =  sy * sx;
            float m01r = -sy * cx, m01i = -cy * sx;
            float m10r =  sy * cx, m10i = -cy * sx;
            float m11r =  cy * cx, m11i = -sy * sx;
            float u0 = cz * m00r + sz * m00i, u1 = cz * m00i - sz * m00r;
            float u2 = cz * m01r + sz * m01i, u3 = cz * m01i - sz * m01r;
            float u4 = cz * m10r - sz * m10i, u5 = cz * m10i + sz * m10r;
            float u6 = cz * m11r - sz * m11i, u7 = cz * m11i + sz * m11r;
            float th = ent[l * (NQ - 1) + c] * 0.5f;
            float c_ = cosf(th), s_ = sinf(th);
            float* o = gF + i * 8;
            o[0] = c_ * u0 - s_ * u4;  o[1] = c_ * u1 - s_ * u5;
            o[2] = c_ * u2 - s_ * u6;  o[3] = c_ * u3 - s_ * u7;
            o[4] = s_ * u0 + c_ * u4;  o[5] = s_ * u1 + c_ * u5;
            o[6] = s_ * u2 + c_ * u6;  o[7] = s_ * u3 + c_ * u7;
        }
        // R20: fused products for the thread-bit CRYs: G = Ry(theta_c)*U_{c+1}, c in {3,7}
        if (t >= 160 && t - 160 < DEPTH * 2) {
            int i = t - 160;              // 0..5
            int l = i >> 1;
            int c = (i & 1) ? 7 : 3;
            int tq = c + 1;
            const float* rr = rot + (l * NQ + tq) * 3;
            float ax = rr[0] * 0.5f, ay = rr[1] * 0.5f, az = rr[2] * 0.5f;
            float cx = cosf(ax), sx = sinf(ax);
            float cy = cosf(ay), sy = sinf(ay);
            float cz = cosf(az), sz = sinf(az);
            float m00r =  cy * cx, m00i =  sy * sx;
            float m01r = -sy * cx, m01i = -cy * sx;
            float m10r =  sy * cx, m10i = -cy * sx;
            float m11r =  cy * cx, m11i = -sy * sx;
            float u0 = cz * m00r + sz * m00i, u1 = cz * m00i - sz * m00r;
            float u2 = cz * m01r + sz * m01i, u3 = cz * m01i - sz * m01r;
            float u4 = cz * m10r - sz * m10i, u5 = cz * m10i + sz * m10r;
            float u6 = cz * m11r - sz * m11i, u7 = cz * m11i + sz * m11r;
            float th = ent[l * (NQ - 1) + c] * 0.5f;
            float c_ = cosf(th), s_ = sinf(th);
            float* o = gG + (l * 2 + (i & 1)) * 8;
            o[0] = c_ * u0 - s_ * u4;  o[1] = c_ * u1 - s_ * u5;
            o[2] = c_ * u2 - s_ * u6;  o[3] = c_ * u3 - s_ * u7;
            o[4] = s_ * u0 + c_ * u4;  o[5] = s_ * u1 + c_ * u5;
            o[6] = s_ * u2 + c_ * u6;  o[7] = s_ * u3 + c_ * u7;
        }
        return;
    }
    int t = threadIdx.x;
    int wv = t >> 6, lane = t & 63;
    int row = blockIdx.x * 4 + wv;              // 1024 blocks x 4 waves = 4096 rows
    const float4* xr = (const float4*)(x + row * IN_SZ) + lane * 2;
    float4 xa = xr[0], xb = xr[1];
    float acc[NQ];
    #pragma unroll
    for (int q = 0; q < NQ; q++) {
        const float4* wr = (const float4*)(w + q * IN_SZ) + lane * 2;
        float4 wa = wr[0], wb = wr[1];
        float d = xa.x*wa.x + xa.y*wa.y + xa.z*wa.z + xa.w*wa.w
                + xb.x*wb.x + xb.y*wb.y + xb.z*wb.z + xb.w*wb.w;
        #pragma unroll
        for (int o = 32; o > 0; o >>= 1) d += __shfl_down(d, o, 64);
        acc[q] = d;
    }
    if (lane == 0) {
        float* er = enc + row * NQ;
        #pragma unroll
        for (int q = 0; q < NQ; q++) er[q] = acc[q] + bvec[q];
    }
}

// ================= K2: batchnorm1 stats — single pass, 1024 threads =================
__global__ void k_bnstats(const float* __restrict__ xm, float* __restrict__ mo,
                          float* __restrict__ ro) {
    __shared__ float scr[32];
    int j = blockIdx.x, t = threadIdx.x;
    float s = 0.f, s2 = 0.f;
    for (int b = t; b < BATCH; b += 1024) {
        float v = xm[b * NQ + j];
        s += v; s2 += v * v;
    }
    #pragma unroll
    for (int o = 32; o > 0; o >>= 1) { s += __shfl_down(s, o, 64); s2 += __shfl_down(s2, o, 64); }
    int lane = t & 63, w = t >> 6;
    if (lane == 0) { scr[w] = s; scr[16 + w] = s2; }
    __syncthreads();
    if (t == 0) {
        float S = 0.f, S2 = 0.f;
        #pragma unroll
        for (int i = 0; i < 16; i++) { S += scr[i]; S2 += scr[16 + i]; }
        float mean = S / (float)BATCH;
        float var  = S2 / (float)BATCH - mean * mean;
        mo[j] = mean;
        ro[j] = 1.f / sqrtf(var + BN_EPS);
    }
}

// ================= K3: quantum circuit — 3-pass schedule + CRY->U fusion =======
// Canonical amp index: qubit q at bit (11-q). Swizzle: slot = idx ^ (((idx>>5)&7)<<1).
// Window A: local bits 3..0 (qubits 8-11, b128); B: bits 7..4; C: bits 11..8.
// 3-pass layer schedule C->B->A by commutation (R14); CRY->U fusion (R15).
// R18: per-block qvec dedup (127.5 -> 117.4, VALU-issue removal == wall time).
// R20: CRY3/CRY7 defusion-by-selection (120.3 -> 113.9). BEST: 192.3 total (R26).
// R27: (a) qvec via per-wave redundant compute + 24 shfl broadcasts — removes the
//      prologue's 2 __syncthreads + LDS round-trip (waves 1-3 idled there anyway;
//      identical op order -> bit-exact). (b) DEPTH loop fully unrolled: all
//      coefficient s_loads get static offsets, hoistable across barriers (G7).
// LESSONS (measured): R10 — no offset hoisting / waves_per_eu (146->163).
// R12 — no 128B-padded atomics. R11 — no grid-scaled redundant stats math.
// R16 — no v2f coefficient tables (vector loads + vmcnt stalls, 126->170).
// R17 — no atomic moment tail (+11 us on k_quantum > one launch saved).
// R19 — no v_pk_*_f32 packed math: HALF-RATE on gfx950 (117.4->120.3).
// R21 — no serialized agent-scope atomic-load reduces (+84 us; atomics don't pipeline).
// R22 — hipMemsetAsync is a dispatch slot too (+8 us); slot count is the metric.
// R23 — NO cooperative grid.sync on MI355X: ~75 us/sync (total 199->430).
// R25 — no s_setprio: timed-neutral but profiled k_quantum 114->127 (VALUBusy
//       70->59%); stall is a barrier/LDS-latency convoy, not issue arbitration.
#define SLA2(j) ((T << 4) | ((((j) ^ ((T >> 1) & 7))) << 1))
#define SLB(m)  (((T & 0xF0) << 4) | ((m) << 4) | ((T & 15) ^ ((m) & 14)))
#define SLC(m)  (((m) << 8) | (T ^ ((((T >> 5) & 7)) << 1)))

#define LDA(j, Ra, Rb) { v4f t_ = *(const v4f*)(xch + SLA2(j));                 \
    Ra = __builtin_shufflevector(t_, t_, 0, 1);                                 \
    Rb = __builtin_shufflevector(t_, t_, 2, 3); }
#define STA(j, Ra, Rb) { v4f t_ = __builtin_shufflevector(Ra, Rb, 0, 1, 2, 3);  \
    *(v4f*)(xch + SLA2(j)) = t_; }

#define LOADA do { LDA(0,s0,s1) LDA(1,s2,s3) LDA(2,s4,s5) LDA(3,s6,s7)          \
    LDA(4,s8,s9) LDA(5,s10,s11) LDA(6,s12,s13) LDA(7,s14,s15) } while (0)
#define STORA do { STA(0,s0,s1) STA(1,s2,s3) STA(2,s4,s5) STA(3,s6,s7)          \
    STA(4,s8,s9) STA(5,s10,s11) STA(6,s12,s13) STA(7,s14,s15) } while (0)

#define LOADW(SL) do {                                                          \
    s0=xch[SL(0)];  s1=xch[SL(1)];  s2=xch[SL(2)];  s3=xch[SL(3)];              \
    s4=xch[SL(4)];  s5=xch[SL(5)];  s6=xch[SL(6)];  s7=xch[SL(7)];              \
    s8=xch[SL(8)];  s9=xch[SL(9)];  s10=xch[SL(10)]; s11=xch[SL(11)];           \
    s12=xch[SL(12)]; s13=xch[SL(13)]; s14=xch[SL(14)]; s15=xch[SL(15)]; } while (0)
#define STORW(SL) do {                                                          \
    xch[SL(0)]=s0;  xch[SL(1)]=s1;  xch[SL(2)]=s2;  xch[SL(3)]=s3;              \
    xch[SL(4)]=s4;  xch[SL(5)]=s5;  xch[SL(6)]=s6;  xch[SL(7)]=s7;              \
    xch[SL(8)]=s8;  xch[SL(9)]=s9;  xch[SL(10)]=s10; xch[SL(11)]=s11;           \
    xch[SL(12)]=s12; xch[SL(13)]=s13; xch[SL(14)]=s14; xch[SL(15)]=s15; } while (0)

#define U_LOADP(uptr) const float* u_ = (uptr);                                  \
    v2f c00r = {u_[0], u_[0]}, c00i = {-u_[1], u_[1]};                           \
    v2f c01r = {u_[2], u_[2]}, c01i = {-u_[3], u_[3]};                           \
    v2f c10r = {u_[4], u_[4]}, c10i = {-u_[5], u_[5]};                           \
    v2f c11r = {u_[6], u_[6]}, c11i = {-u_[7], u_[7]};

#define U_LOADF(uptr) const float* f_ = (uptr);                                  \
    v2f d00r = {f_[0], f_[0]}, d00i = {-f_[1], f_[1]};                           \
    v2f d01r = {f_[2], f_[2]}, d01i = {-f_[3], f_[3]};                           \
    v2f d10r = {f_[4], f_[4]}, d10i = {-f_[5], f_[5]};                           \
    v2f d11r = {f_[6], f_[6]}, d11i = {-f_[7], f_[7]};

// per-lane coefficient select between two wave-uniform 8-float sets (R20)
#define U_LOADSEL(uptr, gptr, cond) const float* u_ = (uptr);                    \
    const float* g_ = (gptr); int k_ = (cond);                                   \
    float e0_ = k_ ? g_[0] : u_[0], e1_ = k_ ? g_[1] : u_[1];                    \
    float e2_ = k_ ? g_[2] : u_[2], e3_ = k_ ? g_[3] : u_[3];                    \
    float e4_ = k_ ? g_[4] : u_[4], e5_ = k_ ? g_[5] : u_[5];                    \
    float e6_ = k_ ? g_[6] : u_[6], e7_ = k_ ? g_[7] : u_[7];                    \
    v2f c00r = {e0_, e0_}, c00i = {-e1_, e1_};                                   \
    v2f c01r = {e2_, e2_}, c01i = {-e3_, e3_};                                   \
    v2f c10r = {e4_, e4_}, c10i = {-e5_, e5_};                                   \
    v2f c11r = {e6_, e6_}, c11i = {-e7_, e7_};

#define U_PAIRP(A, B) { v2f a0 = A, a1 = B, a0s = SW2(a0), a1s = SW2(a1);        \
    A = a0*c00r + a0s*c00i + a1*c01r + a1s*c01i;                                 \
    B = a0*c10r + a0s*c10i + a1*c11r + a1s*c11i; }

#define U_PAIRF(A, B) { v2f a0 = A, a1 = B, a0s = SW2(a0), a1s = SW2(a1);        \
    A = a0*d00r + a0s*d00i + a1*d01r + a1s*d01i;                                 \
    B = a0*d10r + a0s*d10i + a1*d11r + a1s*d11i; }

#define APPLY_U_K3(uptr) do { U_LOADP(uptr)                                      \
    U_PAIRP(s0,s8) U_PAIRP(s1,s9) U_PAIRP(s2,s10) U_PAIRP(s3,s11)                \
    U_PAIRP(s4,s12) U_PAIRP(s5,s13) U_PAIRP(s6,s14) U_PAIRP(s7,s15) } while (0)

// R20: K3 apply with per-lane choice between U and fused Ry*U coefficient sets
#define APPLY_USEL_K3(uptr, gptr, cond) do { U_LOADSEL(uptr, gptr, cond)         \
    U_PAIRP(s0,s8) U_PAIRP(s1,s9) U_PAIRP(s2,s10) U_PAIRP(s3,s11)                \
    U_PAIRP(s4,s12) U_PAIRP(s5,s13) U_PAIRP(s6,s14) U_PAIRP(s7,s15) } while (0)

// fused: gate on bit2, coeff set selected by pair's bit3
#define APPLY_UF_K2(uP, uF) do { U_LOADP(uP) U_LOADF(uF)                         \
    U_PAIRP(s0,s4) U_PAIRP(s1,s5) U_PAIRP(s2,s6) U_PAIRP(s3,s7)                  \
    U_PAIRF(s8,s12) U_PAIRF(s9,s13) U_PAIRF(s10,s14) U_PAIRF(s11,s15) } while (0)
// fused: gate on bit1, selected by bit2
#define APPLY_UF_K1(uP, uF) do { U_LOADP(uP) U_LOADF(uF)                         \
    U_PAIRP(s0,s2) U_PAIRP(s1,s3) U_PAIRF(s4,s6) U_PAIRF(s5,s7)                  \
    U_PAIRP(s8,s10) U_PAIRP(s9,s11) U_PAIRF(s12,s14) U_PAIRF(s13,s15) } while (0)
// fused: gate on bit0, selected by bit1
#define APPLY_UF_K0(uP, uF) do { U_LOADP(uP) U_LOADF(uF)                         \
    U_PAIRP(s0,s1) U_PAIRF(s2,s3) U_PAIRP(s4,s5) U_PAIRF(s6,s7)                  \
    U_PAIRP(s8,s9) U_PAIRF(s10,s11) U_PAIRP(s12,s13) U_PAIRF(s14,s15) } while (0)

#define PRJ(S) ((S).x*(S).x + (S).y*(S).y)
#define WREDUCE(v) { v += __shfl_down(v,32,64); v += __shfl_down(v,16,64);       \
    v += __shfl_down(v,8,64); v += __shfl_down(v,4,64);                          \
    v += __shfl_down(v,2,64); v += __shfl_down(v,1,64); }

__launch_bounds__(256)
__global__ void k_quantum(const float* __restrict__ enc,
                          const float* __restrict__ bn1m, const float* __restrict__ bn1r,
                          const float* __restrict__ g1, const float* __restrict__ b1,
                          const float* __restrict__ gU, const float* __restrict__ gC,
                          const float* __restrict__ gF, const float* __restrict__ gG,
                          float* __restrict__ probs) {
    __shared__ __align__(16) v2f xch[NST];                        // exactly 32 KB

    int T = threadIdx.x, b = blockIdx.x;

    // ---- BN1 + tanh + qvec (R27): per-wave redundant compute, shfl broadcast.
    // Lanes 0..11 of EVERY wave compute h (waves 1-3 would idle at a barrier
    // otherwise); shfl_xor width-16 reduce is the exact op order of R18 ->
    // bit-exact. 24 __shfl broadcasts replace the LDS round-trip + 2 barriers.
    int lane = T & 63;
    float h = 0.f;
    if (lane < NQ) {
        h = tanhf(g1[lane] * (enc[b * NQ + lane] - bn1m[lane]) * bn1r[lane] + b1[lane]);
    }
    float n2 = h * h;
    n2 += __shfl_xor(n2, 1, 16);
    n2 += __shfl_xor(n2, 2, 16);
    n2 += __shfl_xor(n2, 4, 16);
    n2 += __shfl_xor(n2, 8, 16);
    float norm = sqrtf(n2);
    bool  nz   = norm > 0.f;
    float rinv = 1.f / fmaxf(norm, 1e-30f);
    float a_   = nz ? h * rinv : h;
    float amp_ = fminf(fabsf(a_), 1.f);
    float qcv  = sqrtf(fmaxf(1.f - amp_ * amp_, 0.f));
    float qsv  = (a_ < 0.f) ? -amp_ : amp_;
    float qc0  = __shfl(qcv, 0, 64),  qs0  = __shfl(qsv, 0, 64);
    float qc1  = __shfl(qcv, 1, 64),  qs1  = __shfl(qsv, 1, 64);
    float qc2  = __shfl(qcv, 2, 64),  qs2  = __shfl(qsv, 2, 64);
    float qc3  = __shfl(qcv, 3, 64),  qs3  = __shfl(qsv, 3, 64);
    float qc4  = __shfl(qcv, 4, 64),  qs4  = __shfl(qsv, 4, 64);
    float qc5  = __shfl(qcv, 5, 64),  qs5  = __shfl(qsv, 5, 64);
    float qc6  = __shfl(qcv, 6, 64),  qs6  = __shfl(qsv, 6, 64);
    float qc7  = __shfl(qcv, 7, 64),  qs7  = __shfl(qsv, 7, 64);
    float qc8  = __shfl(qcv, 8, 64),  qs8  = __shfl(qsv, 8, 64);
    float qc9  = __shfl(qcv, 9, 64),  qs9  = __shfl(qsv, 9, 64);
    float qc10 = __shfl(qcv, 10, 64), qs10 = __shfl(qsv, 10, 64);
    float qc11 = __shfl(qcv, 11, 64), qs11 = __shfl(qsv, 11, 64);

    v2f s0, s1, s2, s3, s4, s5, s6, s7, s8, s9, s10, s11, s12, s13, s14, s15;

    // ---- pass C, layer 0: init + U0 + fused(U1,CRY0) + fused(U2,CRY1) + fused(U3,CRY2) ----
    {
        float f = ((T>>7)&1 ? qs4 : qc4) * ((T>>6)&1 ? qs5 : qc5)
                * ((T>>5)&1 ? qs6 : qc6) * ((T>>4)&1 ? qs7 : qc7)
                * ((T>>3)&1 ? qs8 : qc8) * ((T>>2)&1 ? qs9 : qc9)
                * ((T>>1)&1 ? qs10 : qc10) * ((T>>0)&1 ? qs11 : qc11);
        // product tree (same left-assoc chains as before -> bit-exact, fewer muls)
        float p0c = f * qc0,  p0s = f * qs0;
        float p00 = p0c*qc1, p01 = p0c*qs1, p10 = p0s*qc1, p11 = p0s*qs1;
        float q000 = p00*qc2, q001 = p00*qs2, q010 = p01*qc2, q011 = p01*qs2;
        float q100 = p10*qc2, q101 = p10*qs2, q110 = p11*qc2, q111 = p11*qs2;
        s0  = (v2f){q000*qc3, 0.f};  s1  = (v2f){q000*qs3, 0.f};
        s2  = (v2f){q001*qc3, 0.f};  s3  = (v2f){q001*qs3, 0.f};
        s4  = (v2f){q010*qc3, 0.f};  s5  = (v2f){q010*qs3, 0.f};
        s6  = (v2f){q011*qc3, 0.f};  s7  = (v2f){q011*qs3, 0.f};
        s8  = (v2f){q100*qc3, 0.f};  s9  = (v2f){q100*qs3, 0.f};
        s10 = (v2f){q101*qc3, 0.f};  s11 = (v2f){q101*qs3, 0.f};
        s12 = (v2f){q110*qc3, 0.f};  s13 = (v2f){q110*qs3, 0.f};
        s14 = (v2f){q111*qc3, 0.f};  s15 = (v2f){q111*qs3, 0.f};
        APPLY_U_K3(gU + 0 * 8);
        APPLY_UF_K2(gU + 1 * 8, gF + 0 * 8);
        APPLY_UF_K1(gU + 2 * 8, gF + 1 * 8);
        APPLY_UF_K0(gU + 3 * 8, gF + 2 * 8);
        STORW(SLC);
    }
    __syncthreads();                          // C->B crosses waves

    #pragma unroll
    for (int l = 0; l < DEPTH; l++) {
        const float* UL = gU + l * 96;
        const float* FL = gF + l * 72;
        const float* GL = gG + l * 16;
        // ---- window B: fused(U4,CRY3 by lane bit) + fused(U5,CRY4) + fused(U6,CRY5) + fused(U7,CRY6) ----
        LOADW(SLB);
        APPLY_USEL_K3(UL + 4 * 8, GL + 0, T & 16);   // CRY3 ctrl = idx bit 8 -> lane bit
        APPLY_UF_K2(UL + 5 * 8, FL + 3 * 8);
        APPLY_UF_K1(UL + 6 * 8, FL + 4 * 8);
        APPLY_UF_K0(UL + 7 * 8, FL + 5 * 8);
        STORW(SLB);
        __builtin_amdgcn_wave_barrier();      // B->A is wave-private
        // ---- window A: fused(U8,CRY7 by lane bit) + fused(U9,CRY8) + fused(U10,CRY9) + fused(U11,CRY10) ----
        LOADA;
        APPLY_USEL_K3(UL + 8 * 8, GL + 8, T & 1);    // CRY7 ctrl = idx bit 4 -> lane bit
        APPLY_UF_K2(UL + 9 * 8, FL + 6 * 8);
        APPLY_UF_K1(UL + 10 * 8, FL + 7 * 8);
        APPLY_UF_K0(UL + 11 * 8, FL + 8 * 8);
        if (l < DEPTH - 1) {
            STORA;
            __syncthreads();                  // A->C crosses waves
            // ---- window C, layer l+1: U0 + fused CRY0-2 ----
            const float* UN = gU + (l + 1) * 96;
            const float* FN = gF + (l + 1) * 72;
            LOADW(SLC);
            APPLY_U_K3(UN + 0 * 8);
            APPLY_UF_K2(UN + 1 * 8, FN + 0 * 8);
            APPLY_UF_K1(UN + 2 * 8, FN + 1 * 8);
            APPLY_UF_K0(UN + 3 * 8, FN + 2 * 8);
            STORW(SLC);
            __syncthreads();                  // C->B crosses waves
        }
    }

    // ---- marginals from registers (window A: idx = T<<4 | m) ----
    float p0 = PRJ(s0),  p1 = PRJ(s1),  p2 = PRJ(s2),  p3 = PRJ(s3);
    float p4 = PRJ(s4),  p5 = PRJ(s5),  p6 = PRJ(s6),  p7 = PRJ(s7);
    float p8 = PRJ(s8),  p9 = PRJ(s9),  p10 = PRJ(s10), p11 = PRJ(s11);
    float p12 = PRJ(s12), p13 = PRJ(s13), p14 = PRJ(s14), p15 = PRJ(s15);
    float tot = p0+p1+p2+p3+p4+p5+p6+p7+p8+p9+p10+p11+p12+p13+p14+p15;
    float r8  = p8+p9+p10+p11+p12+p13+p14+p15;
    float r9  = p4+p5+p6+p7+p12+p13+p14+p15;
    float r10 = p2+p3+p6+p7+p10+p11+p14+p15;
    float r11 = p1+p3+p5+p7+p9+p11+p13+p15;
    // r0/r1 masks (T&128, T&64) are wave-uniform -> derive from one tot-reduce (bit-exact)
    float r2 = (T & 32)  ? tot : 0.f;
    float r3 = (T & 16)  ? tot : 0.f;
    float r4 = (T & 8)   ? tot : 0.f;
    float r5 = (T & 4)   ? tot : 0.f;
    float r6 = (T & 2)   ? tot : 0.f;
    float r7 = (T & 1)   ? tot : 0.f;

    WREDUCE(tot)
    WREDUCE(r2) WREDUCE(r3) WREDUCE(r4) WREDUCE(r5) WREDUCE(r6) WREDUCE(r7)
    WREDUCE(r8) WREDUCE(r9) WREDUCE(r10) WREDUCE(r11)

    __syncthreads();                     // xch no longer needed as state
    float* red = (float*)xch;
    int w = T >> 6;
    if (lane == 0) {
        float* rr = red + w * NQ;
        rr[0] = (w & 2) ? tot : 0.f;
        rr[1] = (w & 1) ? tot : 0.f;
        rr[2]=r2; rr[3]=r3; rr[4]=r4; rr[5]=r5;
        rr[6]=r6; rr[7]=r7; rr[8]=r8; rr[9]=r9; rr[10]=r10; rr[11]=r11;
    }
    __syncthreads();
    if (T < NQ) probs[b * NQ + T] = red[T] + red[NQ + T] + red[2 * NQ + T] + red[3 * NQ + T];
}

// ================= K4: prob moments -> pmean + cov (one pass, 1024 threads) =================
// R24: widened 256 -> 1024 threads (144 blocks cover only ~56% of CUs; kernel is
// latency-bound — 4 strided iterations instead of 16 with 4x the waves).
__global__ void k_pcov(const float* __restrict__ probs, float* __restrict__ pmean,
                       float* __restrict__ cov) {
    __shared__ float scr[48];
    int blk = blockIdx.x;             // 0..143
    int q = blk / NQ, q2 = blk % NQ;
    int t = threadIdx.x;
    float sx = 0.f, sy = 0.f, sxy = 0.f;
    for (int b = t; b < BATCH; b += 1024) {
        float xv = probs[b * NQ + q];
        float yv = probs[b * NQ + q2];
        sx += xv; sy += yv; sxy += xv * yv;
    }
    #pragma unroll
    for (int o = 32; o > 0; o >>= 1) {
        sx += __shfl_down(sx, o, 64);
        sy += __shfl_down(sy, o, 64);
        sxy += __shfl_down(sxy, o, 64);
    }
    int lane = t & 63, w = t >> 6;
    if (lane == 0) { scr[w] = sx; scr[16 + w] = sy; scr[32 + w] = sxy; }
    __syncthreads();
    if (t == 0) {
        float SX = 0.f, SY = 0.f, SXY = 0.f;
        #pragma unroll
        for (int i = 0; i < 16; i++) { SX += scr[i]; SY += scr[16 + i]; SXY += scr[32 + i]; }
        float mx = SX / (float)BATCH, my = SY / (float)BATCH;
        cov[blk] = SXY / (float)BATCH - mx * my;
        if (q == q2) pmean[q] = mx;
    }
}

// ================= K5: final decode + BN2, rstd amortized over 16 rows/block =================
// R26: rstd (156 FMA/thread, the dominant cost) + cv/wv/g2/b2 loads computed ONCE
// per block, then 8 x 2-row iterations. Per-j math/order identical to R24 ->
// bit-exact. Grid 256 blocks x 512 threads (8 waves/CU for this tiny kernel).
__global__ void k_final(const float* __restrict__ probs, const float* __restrict__ pmean,
                        const float* __restrict__ cov, const float* __restrict__ dw,
                        const float* __restrict__ g2, const float* __restrict__ b2,
                        float* __restrict__ out) {
    __shared__ float cp[2][NQ];
    __shared__ float cv[NQ * NQ];
    int t = threadIdx.x;
    int half = t >> 8, j = t & 255;
    if (t < NQ * NQ) cv[t] = cov[t];
    __syncthreads();
    float wv[NQ];
    #pragma unroll
    for (int q = 0; q < NQ; q++) wv[q] = dw[j * NQ + q];
    float var = 0.f;
    #pragma unroll
    for (int q = 0; q < NQ; q++) {
        float a = 0.f;
        #pragma unroll
        for (int q2 = 0; q2 < NQ; q2++) a += cv[q * NQ + q2] * wv[q2];
        var += wv[q] * a;
    }
    float rstd = 1.f / sqrtf(var + BN_EPS);
    float g2t = g2[j], b2t = b2[j];
    #pragma unroll 1
    for (int it = 0; it < 8; it++) {
        int b0 = blockIdx.x * 16 + it * 2;
        __syncthreads();                 // previous iteration's cp reads done
        if (t < NQ)                      cp[0][t]       = probs[b0 * NQ + t]        - pmean[t];
        else if (t >= 256 && t < 256+NQ) cp[1][t - 256] = probs[(b0+1) * NQ + t-256] - pmean[t - 256];
        __syncthreads();
        float acc = 0.f;
        #pragma unroll
        for (int q = 0; q < NQ; q++) acc += cp[half][q] * wv[q];
        out[(b0 + half) * OUT_SZ + j] = acc * rstd * g2t + b2t;
    }
}

extern "C" void kernel_launch(void* const* d_in, const int* in_sizes, int n_in,
                              void* d_out, int out_size, void* d_ws, size_t ws_size,
                              hipStream_t stream) {
    const float* x     = (const float*)d_in[0];
    const float* enc_w = (const float*)d_in[1];
    const float* enc_b = (const float*)d_in[2];
    const float* rot   = (const float*)d_in[3];
    const float* ent   = (const float*)d_in[4];
    const float* dec_w = (const float*)d_in[5];
    // d_in[6] = dec_b — cancels inside BN2
    const float* g1    = (const float*)d_in[7];
    const float* b1    = (const float*)d_in[8];
    const float* g2    = (const float*)d_in[9];
    const float* b2    = (const float*)d_in[10];

    float* ws    = (float*)d_ws;
    float* enc   = ws + OFF_ENC;
    float* bn1m  = ws + OFF_BN1M;
    float* bn1r  = ws + OFF_BN1R;
    float* gU    = ws + OFF_GU;
    float* gC    = ws + OFF_GC;
    float* gF    = ws + OFF_GF;
    float* gG    = ws + OFF_GG;
    float* prb   = ws + OFF_PROBS;
    float* pmean = ws + OFF_PMEAN;
    float* cov   = ws + OFF_COV;

    hipLaunchKernelGGL(k_encode, dim3(1025), dim3(256), 0, stream,
                       x, enc_w, enc_b, rot, ent, enc, gU, gC, gF, gG);
    hipLaunchKernelGGL(k_bnstats, dim3(NQ), dim3(1024), 0, stream, enc, bn1m, bn1r);
    hipLaunchKernelGGL(k_quantum, dim3(BATCH), dim3(256), 0, stream,
                       enc, bn1m, bn1r, g1, b1, gU, gC, gF, gG, prb);
    hipLaunchKernelGGL(k_pcov, dim3(NQ * NQ), dim3(1024), 0, stream, prb, pmean, cov);
    hipLaunchKernelGGL(k_final, dim3(BATCH / 16), dim3(512), 0, stream,
                       prb, pmean, cov, dec_w, g2, b2, (float*)d_out);
}